// Round 10
// baseline (1075.505 us; speedup 1.0000x reference)
//
#include <hip/hip_runtime.h>

#define NN 50000
#define NPAD 50048     // 391 * 128
#define NE 400000
#define NBATCH 8
#define NDIM 32
#define EDIM 16
#define H 128
#define NLAYERS 3
#define CHUNK_ELEMS 4096   // node-kernel weight chunk: 2 hilo * 4 nt * 64 lane * 8
#define NODE_CHUNKS 24     // 16 (Wu, K=256) + 8 (uW2, K=128)
#define ZW_CHUNK 8192      // zdzs chunk: 2 hilo * 8 nt * 64 lane * 8
#define NSB 196            // scan blocks: ceil(50000/256)
#define ZEB 128            // edges per block in ze path (4 waves x 32)

// fused-grid block counts
#define EMB_B 1563                     // embed: 32 nodes/block
#define DEG_B 1563                     // degree: 256 edges/block
#define ZWB (NLAYERS * 8)              // 24
#define WEFB NLAYERS                   // 3 (wef + fused wefs swizzle)
#define WUB (NLAYERS * 257)            // 771
#define P1_B (EMB_B + DEG_B + ZWB + WEFB + WUB)   // 3924
#define K2_B (NSB + NLAYERS * NODE_CHUNKS + NSB)  // 464 (scan1 | wns | counts)
#define ZDZS_B (NPAD / 64)             // 782
#define ZE_B (NE / ZEB)                // 3125
#define ZZ_B (ZDZS_B + ZE_B)           // 3907

typedef __attribute__((ext_vector_type(8))) __bf16 bf16x8;
typedef __attribute__((ext_vector_type(16))) float f32x16;
typedef __attribute__((ext_vector_type(8))) short short8;
typedef __attribute__((ext_vector_type(2))) float v2f;

__device__ __forceinline__ void block_sync_lds() {
  asm volatile("s_waitcnt lgkmcnt(0)\ns_barrier" ::: "memory");
}
// one dword = 2 packed bf16 -> 2 fp32 (pure bit ops)
__device__ __forceinline__ v2f bf2f(unsigned u) {
  v2f r;
  r.x = __uint_as_float(u << 16);
  r.y = __uint_as_float(u & 0xffff0000u);
  return r;
}

// ================= P1: embed | degree | precomp_zw | precomp_wef(+wefs) | precomp_wu ===
__global__ __launch_bounds__(256) void p1_kernel(
    const float* __restrict__ x, const float* __restrict__ Wn,
    const float* __restrict__ bn, __bf16* __restrict__ hb,
    const int* __restrict__ ei, int* __restrict__ deg,
    const float* __restrict__ mW1, __bf16* __restrict__ ZW,
    const float* __restrict__ mb1, const float* __restrict__ We,
    const float* __restrict__ be, __bf16* __restrict__ WefS,
    float* __restrict__ bm, const float* __restrict__ uW1,
    const float* __restrict__ mW2, const float* __restrict__ mb2,
    float* __restrict__ Wu, float* __restrict__ va) {
  __shared__ __align__(16) float smem[NDIM * H + 32 * NDIM];  // 20 KB
  int bi = blockIdx.x;
  int tid = threadIdx.x;
  if (bi < EMB_B) {
    // ---- embed: h = x @ Wn + bn, 32 nodes/block ----
    float* Ws = smem;
    float* xs = smem + NDIM * H;
    int nbase = bi * 32;
    for (int f = tid; f < NDIM * H; f += 256) Ws[f] = Wn[f];
    for (int f = tid; f < 32 * NDIM; f += 256) {
      int gi = nbase * NDIM + f;
      xs[f] = (gi < NN * NDIM) ? x[gi] : 0.f;
    }
    __syncthreads();
    int j = tid & 127, g = tid >> 7;
    float wcol[NDIM];
#pragma unroll
    for (int k = 0; k < NDIM; ++k) wcol[k] = Ws[k * H + j];
    float b = bn[j];
    for (int nn = 0; nn < 16; ++nn) {
      int node = nbase + g * 16 + nn;
      if (node < NN) {
        float acc = b;
        const float4* xv = (const float4*)&xs[(g * 16 + nn) * NDIM];
#pragma unroll
        for (int k4 = 0; k4 < NDIM / 4; ++k4) {
          float4 v = xv[k4];
          acc = fmaf(v.x, wcol[k4 * 4 + 0], acc);
          acc = fmaf(v.y, wcol[k4 * 4 + 1], acc);
          acc = fmaf(v.z, wcol[k4 * 4 + 2], acc);
          acc = fmaf(v.w, wcol[k4 * 4 + 3], acc);
        }
        hb[(size_t)node * H + j] = (__bf16)acc;
      }
    }
  } else if (bi < EMB_B + DEG_B) {
    // ---- degree histogram over dst ----
    int e = (bi - EMB_B) * 256 + tid;
    if (e < NE) atomicAdd(&deg[ei[NE + e]], 1);
  } else if (bi < EMB_B + DEG_B + ZWB) {
    // ---- zdzs weights: mW1[0:256] -> hi/lo bf16, frag-swizzled ----
    int bb = bi - EMB_B - DEG_B;
    int l = bb / 8;
    int c = bb % 8;
    const float* w1 = mW1 + (size_t)l * 384 * H;
    __bf16* dst = ZW + ((size_t)l * 8 + c) * ZW_CHUNK;
    for (int it = 0; it < 32; it += 4) {
      float wv[4];
#pragma unroll
      for (int q = 0; q < 4; ++q) {
        int flat = (it + q) * 256 + tid;
        int j = flat & 7;
        int lane = (flat >> 3) & 63;
        int nt = (flat >> 9) & 7;
        int k = c * 16 + ((lane >> 5) << 3) + j;
        int n = nt * 32 + (lane & 31);
        wv[q] = (n < 128) ? w1[(size_t)k * H + n]
                          : w1[(size_t)(128 + k) * H + (n - 128)];
      }
#pragma unroll
      for (int q = 0; q < 4; ++q) {
        int flat = (it + q) * 256 + tid;
        int hilo = flat >> 12;
        __bf16 hi = (__bf16)wv[q];
        __bf16 lo = (__bf16)(wv[q] - (float)hi);
        dst[flat] = hilo ? lo : hi;
      }
    }
  } else if (bi < EMB_B + DEG_B + ZWB + WEFB) {
    // ---- Wef = We @ mW1[256:384] -> swizzled WefS directly (LDS transpose) ----
    int l = bi - (EMB_B + DEG_B + ZWB);
    float* WeS = smem;            // 2048
    float* beS = smem + 2048;     // 128
    float* wefT = smem + 2176;    // 2048: Wef[k][n] transpose buffer
    for (int f = tid; f < EDIM * H; f += 256) WeS[f] = We[f];
    if (tid < 128) beS[tid] = be[tid];
    __syncthreads();
    if (tid < 128) {
      int n = tid;
      const float* w1 = mW1 + (size_t)l * 384 * H + (size_t)256 * H + n;
      float acc[EDIM];
#pragma unroll
      for (int i = 0; i < EDIM; ++i) acc[i] = 0.f;
      float accb = 0.f;
      for (int c = 0; c < H; c += 4) {
        float w0 = w1[(size_t)(c + 0) * H];
        float w1v = w1[(size_t)(c + 1) * H];
        float w2 = w1[(size_t)(c + 2) * H];
        float w3 = w1[(size_t)(c + 3) * H];
        accb = fmaf(beS[c + 0], w0, accb);
        accb = fmaf(beS[c + 1], w1v, accb);
        accb = fmaf(beS[c + 2], w2, accb);
        accb = fmaf(beS[c + 3], w3, accb);
#pragma unroll
        for (int i = 0; i < EDIM; ++i) {
          acc[i] = fmaf(WeS[i * H + c + 0], w0, acc[i]);
          acc[i] = fmaf(WeS[i * H + c + 1], w1v, acc[i]);
          acc[i] = fmaf(WeS[i * H + c + 2], w2, acc[i]);
          acc[i] = fmaf(WeS[i * H + c + 3], w3, acc[i]);
        }
      }
#pragma unroll
      for (int i = 0; i < EDIM; ++i) wefT[i * H + n] = acc[i];
      bm[l * H + n] = mb1[l * H + n] + accb;
    }
    __syncthreads();
    {
      int nt = tid >> 6, lane = tid & 63;
      int n = nt * 32 + (lane & 31);
      int half = lane >> 5;
      __bf16* dst = WefS + (size_t)l * CHUNK_ELEMS;
#pragma unroll
      for (int j = 0; j < 8; ++j) {
        int k = half * 8 + j;
        float w = wefT[k * H + n];
        __bf16 hi = (__bf16)w;
        __bf16 lo = (__bf16)(w - (float)hi);
        dst[((0 * 4 + nt) * 64 + lane) * 8 + j] = hi;
        dst[((1 * 4 + nt) * 64 + lane) * 8 + j] = lo;
      }
    }
  } else {
    // ---- folded update weights (fp32 Wu / va): half-split K, LDS row ----
    int bb = bi - (EMB_B + DEG_B + ZWB + WEFB);
    int l = bb / 257;
    int r = bb % 257;
    int j = tid & 127, hf = tid >> 7;
    const float* u1 = uW1 + (size_t)l * 256 * H;
    if (r < 128) {
      if (tid < 128) Wu[((size_t)l * 256 + r) * H + j] = u1[(size_t)r * H + j];
    } else {
      float* rowS = smem;        // 128: broadcast row
      float* redS = smem + 128;  // 128: cross-half partial
      if (tid < 128)
        rowS[tid] = (r < 256) ? mW2[((size_t)l * H + (r - 128)) * H + tid]
                              : mb2[l * H + tid];
      __syncthreads();
      int cb = hf * 64;
      float s0 = 0.f, s1 = 0.f, s2 = 0.f, s3 = 0.f;
      for (int c = 0; c < 64; c += 4) {
        float a0 = u1[(size_t)(128 + cb + c + 0) * H + j];
        float a1 = u1[(size_t)(128 + cb + c + 1) * H + j];
        float a2 = u1[(size_t)(128 + cb + c + 2) * H + j];
        float a3 = u1[(size_t)(128 + cb + c + 3) * H + j];
        s0 = fmaf(rowS[cb + c + 0], a0, s0);
        s1 = fmaf(rowS[cb + c + 1], a1, s1);
        s2 = fmaf(rowS[cb + c + 2], a2, s2);
        s3 = fmaf(rowS[cb + c + 3], a3, s3);
      }
      float s = (s0 + s1) + (s2 + s3);
      if (hf == 1) redS[j] = s;
      __syncthreads();
      if (hf == 0) {
        float tot = s + redS[j];
        if (r < 256) Wu[((size_t)l * 256 + r) * H + j] = tot;
        else va[l * H + j] = tot;
      }
    }
  }
}

// ================= K2: scan1 | precomp_wns | batch counts ===
__global__ __launch_bounds__(256) void k2_kernel(
    const int* __restrict__ deg, int* __restrict__ bsum,
    const float* __restrict__ Wu, const float* __restrict__ uW2,
    __bf16* __restrict__ WnS, const int* __restrict__ batch,
    int* __restrict__ counts) {
  __shared__ int ws[4];
  int bi = blockIdx.x;
  int tid = threadIdx.x;
  if (bi < NSB) {
    // ---- scan1: per-block degree sums ----
    int i = bi * 256 + tid;
    int lane = tid & 63, wid = tid >> 6;
    int v = (i < NN) ? deg[i] : 0;
#pragma unroll
    for (int off = 32; off; off >>= 1) v += __shfl_down(v, off);
    if (lane == 0) ws[wid] = v;
    __syncthreads();
    if (tid == 0) bsum[bi] = ws[0] + ws[1] + ws[2] + ws[3];
  } else if (bi < NSB + NLAYERS * NODE_CHUNKS) {
    // ---- swizzle node weights into hi/lo frag chunks ----
    int idx = bi - NSB;
    int l = idx / NODE_CHUNKS;
    int c = idx % NODE_CHUNKS;
    int nt = tid >> 6, lane = tid & 63;
    int n = nt * 32 + (lane & 31);
    int half = lane >> 5;
    __bf16* dst = WnS + ((size_t)l * NODE_CHUNKS + c) * CHUNK_ELEMS;
#pragma unroll
    for (int j = 0; j < 8; ++j) {
      float w;
      if (c < 16) {
        int k = c * 16 + half * 8 + j;
        w = Wu[((size_t)l * 256 + k) * H + n];
      } else {
        int k = (c - 16) * 16 + half * 8 + j;
        w = uW2[((size_t)l * H + k) * H + n];
      }
      __bf16 hi = (__bf16)w;
      __bf16 lo = (__bf16)(w - (float)hi);
      dst[((0 * 4 + nt) * 64 + lane) * 8 + j] = hi;
      dst[((1 * 4 + nt) * 64 + lane) * 8 + j] = lo;
    }
  } else {
    // ---- batch counts (batch layer-invariant; pool fused into last nu) ----
    int i = (bi - NSB - NLAYERS * NODE_CHUNKS) * 256 + tid;
    if (i < NN) atomicAdd(&counts[batch[i]], 1);
  }
}

// ---------------- scan3 (with scan2 folded in: each block scans bsum locally) ----
__global__ __launch_bounds__(256) void scan3_kernel(const int* __restrict__ deg,
                                                    const int* __restrict__ bsum,
                                                    int* __restrict__ cursor) {
  __shared__ int s[256];
  __shared__ int wsum[4], woff[4];
  int t = threadIdx.x;
  int bv = (t < NSB) ? bsum[t] : 0;
  s[t] = bv;
  __syncthreads();
  for (int off = 1; off < 256; off <<= 1) {
    int u = (t >= off) ? s[t - off] : 0;
    __syncthreads();
    s[t] += u;
    __syncthreads();
  }
  int boff_b = s[blockIdx.x] - bsum[blockIdx.x];  // exclusive prefix for this block
  __syncthreads();

  int i = blockIdx.x * 256 + t;
  int lane = t & 63, wid = t >> 6;
  int orig = (i < NN) ? deg[i] : 0;
  int v = orig;
#pragma unroll
  for (int off = 1; off < 64; off <<= 1) {
    int u = __shfl_up(v, off);
    if (lane >= off) v += u;
  }
  if (lane == 63) wsum[wid] = v;
  __syncthreads();
  if (t == 0) {
    int r = 0;
#pragma unroll
    for (int w = 0; w < 4; ++w) {
      woff[w] = r;
      r += wsum[w];
    }
  }
  __syncthreads();
  if (i < NN) cursor[i] = (v - orig) + woff[wid] + boff_b;
}

// ---------------- counting-sort scatter + ea gather fused ----------------
__global__ __launch_bounds__(256) void scatter_kernel(
    const int* __restrict__ ei, int* __restrict__ cursor,
    int* __restrict__ srcSrt, const float* __restrict__ ea,
    __bf16* __restrict__ eaSrt) {
  int e = blockIdx.x * 256 + threadIdx.x;
  if (e < NE) {
    int d = ei[NE + e];
    int s = ei[e];
    const float4* ep = (const float4*)(ea + (size_t)e * EDIM);
    float4 v0 = ep[0], v1 = ep[1], v2 = ep[2], v3 = ep[3];
    int pos = atomicAdd(&cursor[d], 1);
    srcSrt[pos] = s;
    union { __bf16 b[16]; uint4 u[2]; } pk;
    pk.b[0] = (__bf16)v0.x;  pk.b[1] = (__bf16)v0.y;
    pk.b[2] = (__bf16)v0.z;  pk.b[3] = (__bf16)v0.w;
    pk.b[4] = (__bf16)v1.x;  pk.b[5] = (__bf16)v1.y;
    pk.b[6] = (__bf16)v1.z;  pk.b[7] = (__bf16)v1.w;
    pk.b[8] = (__bf16)v2.x;  pk.b[9] = (__bf16)v2.y;
    pk.b[10] = (__bf16)v2.z; pk.b[11] = (__bf16)v2.w;
    pk.b[12] = (__bf16)v3.x; pk.b[13] = (__bf16)v3.y;
    pk.b[14] = (__bf16)v3.z; pk.b[15] = (__bf16)v3.w;
    uint4* op = (uint4*)(eaSrt + (size_t)pos * EDIM);
    op[0] = pk.u[0];
    op[1] = pk.u[1];
  }
}

// ================= ZZ: zdzs (782 blocks) | ze (3125 blocks), one dispatch =====
__global__ __launch_bounds__(256) void zz_kernel(
    const __bf16* __restrict__ hb, const __bf16* __restrict__ ZW,
    const float* __restrict__ bm, __bf16* __restrict__ z,
    const __bf16* __restrict__ eaSrt, const __bf16* __restrict__ WefS,
    __bf16* __restrict__ zePre) {
  __shared__ __align__(16) __bf16 Bt[2][ZW_CHUNK];  // 32 KB
  int bi = blockIdx.x;
  int tid = threadIdx.x;
  int wid = tid >> 6, lane = tid & 63, m = lane & 31, half = lane >> 5;
  if (bi < ZDZS_B) {
    // ---- zdzs: z = h @ [W_d|W_s] (+bm on dst half), 64 rows/block ----
    int rg = wid & 1;   // 32-row group
    int nh = wid >> 1;  // nt quad
    int nb = bi * 64;
    int row = nb + rg * 32 + m;
    const __bf16* aH = hb + (size_t)row * H + half * 8;
    const short8* gW = (const short8*)ZW;  // 1024 short8 per chunk
    short8* sB0 = (short8*)&Bt[0][0];
    short8* sB1 = (short8*)&Bt[1][0];
#pragma unroll
    for (int q = 0; q < 4; ++q) sB0[tid + q * 256] = gW[tid + q * 256];
    short8 p0 = gW[1024 + tid], p1 = gW[1024 + tid + 256];
    short8 p2 = gW[1024 + tid + 512], p3 = gW[1024 + tid + 768];
    f32x16 acc[4];
#pragma unroll
    for (int ntl = 0; ntl < 4; ++ntl)
#pragma unroll
      for (int r = 0; r < 16; ++r) acc[ntl][r] = 0.f;
    bf16x8 a = *(const bf16x8*)aH;
    block_sync_lds();

    for (int s = 0; s < 8; ++s) {
      int buf = s & 1;
      bf16x8 na = a;
      if (s + 1 < 8) na = *(const bf16x8*)(aH + (s + 1) * 16);
      if (s + 1 < 8) {
        short8* sb = buf ? sB0 : sB1;
        sb[tid] = p0;
        sb[tid + 256] = p1;
        sb[tid + 512] = p2;
        sb[tid + 768] = p3;
        if (s + 2 < 8) {
          p0 = gW[(size_t)(s + 2) * 1024 + tid];
          p1 = gW[(size_t)(s + 2) * 1024 + tid + 256];
          p2 = gW[(size_t)(s + 2) * 1024 + tid + 512];
          p3 = gW[(size_t)(s + 2) * 1024 + tid + 768];
        }
      }
      const __bf16* bb = &Bt[buf][0];
#pragma unroll
      for (int ntl = 0; ntl < 4; ++ntl) {
        int nt = nh * 4 + ntl;
        bf16x8 bh = *(const bf16x8*)&bb[((0 * 8 + nt) * 64 + lane) * 8];
        bf16x8 bl = *(const bf16x8*)&bb[((1 * 8 + nt) * 64 + lane) * 8];
        acc[ntl] = __builtin_amdgcn_mfma_f32_32x32x16_bf16(a, bh, acc[ntl], 0, 0, 0);
        acc[ntl] = __builtin_amdgcn_mfma_f32_32x32x16_bf16(a, bl, acc[ntl], 0, 0, 0);
      }
      a = na;
      if (s + 1 < 8) block_sync_lds();
    }

    float bmv[4];
#pragma unroll
    for (int ntl = 0; ntl < 4; ++ntl) {
      int nt = nh * 4 + ntl;
      bmv[ntl] = (nt < 4) ? bm[nt * 32 + m] : 0.f;
    }
#pragma unroll
    for (int ntl = 0; ntl < 4; ++ntl) {
      int nt = nh * 4 + ntl;
#pragma unroll
      for (int r = 0; r < 16; ++r) {
        int rowi = (r & 3) + 8 * (r >> 2) + 4 * half;
        z[(size_t)(nb + rg * 32 + rowi) * 256 + nt * 32 + m] =
            (__bf16)(acc[ntl][r] + bmv[ntl]);
      }
    }
  } else {
    // ---- ze: zePre[e] = eaSrt[e] @ Wef, MFMA K=16 ----
    __bf16* Bf = &Bt[0][0];
    ((short8*)Bf)[tid] = ((const short8*)WefS)[tid];
    ((short8*)Bf)[tid + 256] = ((const short8*)WefS)[tid + 256];
    int ebase = (bi - ZDZS_B) * ZEB + wid * 32;
    bf16x8 a = *(const bf16x8*)(eaSrt + (size_t)(ebase + m) * EDIM + half * 8);
    f32x16 acc[4];
#pragma unroll
    for (int nt = 0; nt < 4; ++nt)
#pragma unroll
      for (int r = 0; r < 16; ++r) acc[nt][r] = 0.f;
    block_sync_lds();
#pragma unroll
    for (int nt = 0; nt < 4; ++nt) {
      bf16x8 bh = *(const bf16x8*)&Bf[((0 * 4 + nt) * 64 + lane) * 8];
      bf16x8 bl = *(const bf16x8*)&Bf[((1 * 4 + nt) * 64 + lane) * 8];
      acc[nt] = __builtin_amdgcn_mfma_f32_32x32x16_bf16(a, bh, acc[nt], 0, 0, 0);
      acc[nt] = __builtin_amdgcn_mfma_f32_32x32x16_bf16(a, bl, acc[nt], 0, 0, 0);
    }
#pragma unroll
    for (int nt = 0; nt < 4; ++nt) {
#pragma unroll
      for (int r = 0; r < 16; ++r) {
        int rowi = (r & 3) + 8 * (r >> 2) + 4 * half;
        zePre[(size_t)(ebase + rowi) * H + nt * 32 + m] = (__bf16)acc[nt][r];
      }
    }
  }
}

// ---------------- node-parallel CSR aggregation: aggr[n] = sum relu(zd+zs+ze) ----
// 8-deep gather batches (avg degree 8 -> one L3-latency wait per node instead
// of two with the old 4-deep version).
__global__ __launch_bounds__(256) void edge_aggr_kernel(
    const __bf16* __restrict__ z, const int* __restrict__ srcSrt,
    const int* __restrict__ cend, const __bf16* __restrict__ zePre,
    __bf16* __restrict__ aggrB) {
  int node = blockIdx.x * 4 + (threadIdx.x >> 6);
  int lane = threadIdx.x & 63;
  int c0 = lane * 2;
  int end = cend[node];
  int start = node ? cend[node - 1] : 0;
  v2f acc = {0.f, 0.f};
  if (start < end) {
    v2f zd = bf2f(*(const unsigned*)(z + (size_t)node * 256 + c0));
    int sArr[8];
#pragma unroll
    for (int p = 0; p < 8; ++p)
      if (start + p < end) sArr[p] = srcSrt[start + p];
    for (int e0 = start; e0 < end; e0 += 8) {
      unsigned zsb[8], zeb[8];
#pragma unroll
      for (int p = 0; p < 8; ++p) {
        if (e0 + p < end) {
          zsb[p] = *(const unsigned*)(z + (size_t)sArr[p] * 256 + 128 + c0);
          zeb[p] = *(const unsigned*)(zePre + (size_t)(e0 + p) * H + c0);
        }
      }
#pragma unroll
      for (int p = 0; p < 8; ++p)
        if (e0 + 8 + p < end) sArr[p] = srcSrt[e0 + 8 + p];
#pragma unroll
      for (int p = 0; p < 8; ++p) {
        if (e0 + p < end) {
          v2f t = zd + bf2f(zsb[p]) + bf2f(zeb[p]);
          acc.x += fmaxf(t.x, 0.f);
          acc.y += fmaxf(t.y, 0.f);
        }
      }
    }
  }
  union { __bf16 b[2]; unsigned u; } pk;
  pk.b[0] = (__bf16)acc.x;
  pk.b[1] = (__bf16)acc.y;
  *(unsigned*)(aggrB + (size_t)node * H + c0) = pk.u;
}

// ---------------- MFMA fused node update (h bf16), 64 rows/block --------------
// doPool (last layer): mean-pool fused into the epilogue -- final h values are
// in registers, accumulate into LDS pS (aliases Bt, dead after last MFMA),
// then one sparse global-atomic flush. Saves the pool dispatch + hb re-read.
__global__ __launch_bounds__(256) void node_update_mfma_kernel(
    __bf16* __restrict__ hb, const __bf16* __restrict__ aggrB,
    const int* __restrict__ deg, const __bf16* __restrict__ WnS,
    const float* __restrict__ ub1, const float* __restrict__ va,
    const float* __restrict__ ub2, const int* __restrict__ batch,
    float* __restrict__ pooled, int doPool) {
  __shared__ __align__(16) __bf16 Bt[2][CHUNK_ELEMS];  // 16 KB
  __shared__ __bf16 hid[2][32][132];                   // 16.9 KB
  __shared__ float degS[64];
  int tid = threadIdx.x;
  int nb = blockIdx.x * 64;
  if (tid < 64) degS[tid] = (float)deg[nb + tid];
  int wid = tid >> 6, lane = tid & 63, m = lane & 31, half = lane >> 5;
  int rg = wid & 1;        // row group (32 rows)
  int nh = wid >> 1;       // col half (2 nt slots)
  int row = nb + rg * 32 + m;
  const __bf16* aHb = hb + (size_t)row * H + half * 8;
  const __bf16* aGb = aggrB + (size_t)row * H + half * 8;
  const short8* gW = (const short8*)WnS;
  short8* sB0 = (short8*)&Bt[0][0];
  short8* sB1 = (short8*)&Bt[1][0];
  sB0[tid] = gW[tid];
  sB0[tid + 256] = gW[tid + 256];
  short8 p0 = gW[512 + tid], p1 = gW[512 + tid + 256];
  float bv1[2], bva[2];
#pragma unroll
  for (int ntl = 0; ntl < 2; ++ntl) {
    int nt = nh * 2 + ntl;
    bv1[ntl] = ub1[nt * 32 + m];
    bva[ntl] = va[nt * 32 + m];
  }
  f32x16 acc[2];
#pragma unroll
  for (int ntl = 0; ntl < 2; ++ntl)
#pragma unroll
    for (int r = 0; r < 16; ++r) acc[ntl][r] = 0.f;
  bf16x8 acur = *(const bf16x8*)aHb;
  block_sync_lds();

  for (int s = 0; s < 16; ++s) {
    int buf = s & 1;
    bf16x8 anext = acur;
    if (s + 1 < 16) {
      int sp = s + 1;
      anext = (sp < 8) ? *(const bf16x8*)(aHb + sp * 16)
                       : *(const bf16x8*)(aGb + (sp - 8) * 16);
    }
    {
      short8* sb = buf ? sB0 : sB1;
      sb[tid] = p0;
      sb[tid + 256] = p1;
      if (s + 2 < NODE_CHUNKS) {
        p0 = gW[(size_t)(s + 2) * 512 + tid];
        p1 = gW[(size_t)(s + 2) * 512 + tid + 256];
      }
    }
    const __bf16* bb = &Bt[buf][0];
#pragma unroll
    for (int ntl = 0; ntl < 2; ++ntl) {
      int nt = nh * 2 + ntl;
      bf16x8 bh = *(const bf16x8*)&bb[((0 * 4 + nt) * 64 + lane) * 8];
      bf16x8 bl = *(const bf16x8*)&bb[((1 * 4 + nt) * 64 + lane) * 8];
      acc[ntl] = __builtin_amdgcn_mfma_f32_32x32x16_bf16(acur, bh, acc[ntl], 0, 0, 0);
      acc[ntl] = __builtin_amdgcn_mfma_f32_32x32x16_bf16(acur, bl, acc[ntl], 0, 0, 0);
    }
    acur = anext;
    block_sync_lds();
  }

#pragma unroll
  for (int ntl = 0; ntl < 2; ++ntl) {
    int nt = nh * 2 + ntl;
#pragma unroll
    for (int r = 0; r < 16; ++r) {
      int rowi = (r & 3) + 8 * (r >> 2) + 4 * half;
      float v = acc[ntl][r] + bv1[ntl] + degS[rg * 32 + rowi] * bva[ntl];
      hid[rg][rowi][nt * 32 + m] = (__bf16)fmaxf(v, 0.f);
      acc[ntl][r] = 0.f;
    }
  }
  // hid cols are split across the two nh waves of each row group ->
  // full barrier before any wave reads hid.
  block_sync_lds();

  for (int s = 16; s < NODE_CHUNKS; ++s) {
    int buf = s & 1;
    if (s + 1 < NODE_CHUNKS) {
      short8* sb = buf ? sB0 : sB1;
      sb[tid] = p0;
      sb[tid + 256] = p1;
      if (s + 2 < NODE_CHUNKS) {
        p0 = gW[(size_t)(s + 2) * 512 + tid];
        p1 = gW[(size_t)(s + 2) * 512 + tid + 256];
      }
    }
    bf16x8 ah = *(const bf16x8*)&hid[rg][m][(s - 16) * 16 + half * 8];
    const __bf16* bb = &Bt[buf][0];
#pragma unroll
    for (int ntl = 0; ntl < 2; ++ntl) {
      int nt = nh * 2 + ntl;
      bf16x8 bh = *(const bf16x8*)&bb[((0 * 4 + nt) * 64 + lane) * 8];
      bf16x8 bl = *(const bf16x8*)&bb[((1 * 4 + nt) * 64 + lane) * 8];
      acc[ntl] = __builtin_amdgcn_mfma_f32_32x32x16_bf16(ah, bh, acc[ntl], 0, 0, 0);
      acc[ntl] = __builtin_amdgcn_mfma_f32_32x32x16_bf16(ah, bl, acc[ntl], 0, 0, 0);
    }
    if (s + 1 < NODE_CHUNKS) block_sync_lds();
  }

  float* pS = (float*)&Bt[0][0];       // 1024 floats (4 KB), Bt dead now
  int* bS = (int*)&hid[0][0][0];       // 64 ints, hid dead now
  if (doPool) {
    block_sync_lds();  // all waves done reading Bt/hid
    if (tid < 64) bS[tid] = (nb + tid < NN) ? batch[nb + tid] : -1;
    for (int i = tid; i < NBATCH * H; i += 256) pS[i] = 0.f;
    block_sync_lds();
  }

#pragma unroll
  for (int ntl = 0; ntl < 2; ++ntl) {
    int nt = nh * 2 + ntl;
    float b2 = ub2[nt * 32 + m];
#pragma unroll
    for (int r = 0; r < 16; ++r) {
      int rowi = (r & 3) + 8 * (r >> 2) + 4 * half;
      int lr2 = rg * 32 + rowi;
      size_t idx = (size_t)(nb + lr2) * H + nt * 32 + m;
      float hv = (float)hb[idx];
      float val = hv + acc[ntl][r] + b2;
      hb[idx] = (__bf16)val;
      if (doPool) {
        int b = bS[lr2];
        if (b >= 0) {
          float pv = (float)(__bf16)val;  // match pooling of rounded bf16 h
          atomicAdd(&pS[b * H + nt * 32 + m], pv);
        }
      }
    }
  }

  if (doPool) {
    block_sync_lds();
    for (int i = tid; i < NBATCH * H; i += 256) {
      float v = pS[i];
      if (v != 0.f) unsafeAtomicAdd(&pooled[i], v);
    }
  }
}

// ---------------- readout MLP: one block per batch ----------------
__global__ __launch_bounds__(128) void readout_kernel(
    const float* __restrict__ pooled, const int* __restrict__ counts,
    const float* __restrict__ gf, const float* __restrict__ Wg,
    const float* __restrict__ bg, const float* __restrict__ rW1,
    const float* __restrict__ rb1, const float* __restrict__ rW2,
    const float* __restrict__ rb2, const float* __restrict__ rW3,
    const float* __restrict__ rb3, float* __restrict__ out) {
  __shared__ float fin[256];
  __shared__ float t1[128];
  __shared__ float t2[64];
  int j = threadIdx.x;
  int b = blockIdx.x;
  float cnt = (float)counts[b];
  if (cnt < 1.f) cnt = 1.f;
  fin[j] = pooled[b * H + j] / cnt;
  fin[H + j] = fmaf(gf[b], Wg[j], bg[j]);
  __syncthreads();
  float a = rb1[j];
  for (int k = 0; k < 256; ++k) a = fmaf(fin[k], rW1[k * H + j], a);
  t1[j] = fmaxf(a, 0.f);
  __syncthreads();
  if (j < 64) {
    float a2 = rb2[j];
    for (int k = 0; k < 128; ++k) a2 = fmaf(t1[k], rW2[k * 64 + j], a2);
    t2[j] = fmaxf(a2, 0.f);
  }
  __syncthreads();
  if (j < 64) {
    float p = t2[j] * rW3[j];
#pragma unroll
    for (int off = 32; off; off >>= 1) p += __shfl_down(p, off);
    if (j == 0) out[b] = p + rb3[0];
  }
}

extern "C" void kernel_launch(void* const* d_in, const int* in_sizes, int n_in,
                              void* d_out, int out_size, void* d_ws, size_t ws_size,
                              hipStream_t stream) {
  const float* x   = (const float*)d_in[0];
  const float* ea  = (const float*)d_in[1];
  const float* gf  = (const float*)d_in[2];
  const int*   ei  = (const int*)d_in[3];
  const int*   bat = (const int*)d_in[4];
  const float* Wn  = (const float*)d_in[5];
  const float* bn  = (const float*)d_in[6];
  const float* We  = (const float*)d_in[7];
  const float* be  = (const float*)d_in[8];
  const float* Wg  = (const float*)d_in[9];
  const float* bg  = (const float*)d_in[10];
  const float* mW1 = (const float*)d_in[11];
  const float* mb1 = (const float*)d_in[12];
  const float* mW2 = (const float*)d_in[13];
  const float* mb2 = (const float*)d_in[14];
  const float* uW1 = (const float*)d_in[15];
  const float* ub1 = (const float*)d_in[16];
  const float* uW2 = (const float*)d_in[17];
  const float* ub2 = (const float*)d_in[18];
  const float* rW1 = (const float*)d_in[19];
  const float* rb1 = (const float*)d_in[20];
  const float* rW2 = (const float*)d_in[21];
  const float* rb2 = (const float*)d_in[22];
  const float* rW3 = (const float*)d_in[23];
  const float* rb3 = (const float*)d_in[24];

  char* p = (char*)d_ws;
  __bf16* hb     = (__bf16*)p; p += (size_t)NPAD * H * 2;        // 12.8 MB
  __bf16* aggrB  = (__bf16*)p; p += (size_t)NPAD * H * 2;        // 12.8 MB
  __bf16* z      = (__bf16*)p; p += (size_t)NPAD * 256 * 2;      // 25.6 MB
  __bf16* zePre  = (__bf16*)p; p += (size_t)NE * H * 2;          // 102.4 MB
  __bf16* eaSrt  = (__bf16*)p; p += (size_t)NE * EDIM * 2;       // 12.8 MB
  int*    srcSrt = (int*)p;    p += (size_t)NE * 4;              // 1.6 MB
  __bf16* ZW     = (__bf16*)p; p += (size_t)NLAYERS * 8 * ZW_CHUNK * 2;
  __bf16* WnS    = (__bf16*)p; p += (size_t)NLAYERS * NODE_CHUNKS * CHUNK_ELEMS * 2;
  __bf16* WefS   = (__bf16*)p; p += (size_t)NLAYERS * CHUNK_ELEMS * 2;
  float*  bm     = (float*)p;  p += (size_t)NLAYERS * H * 4;
  float*  Wu     = (float*)p;  p += (size_t)NLAYERS * 256 * H * 4;
  float*  va     = (float*)p;  p += (size_t)NLAYERS * H * 4;
  int*    deg    = (int*)p;    p += (size_t)NPAD * 4;
  int*    cursor = (int*)p;    p += (size_t)NPAD * 4;
  int*    bsum   = (int*)p;    p += 256 * 4;
  float*  pooled = (float*)p;  p += (size_t)NBATCH * H * 4;
  int*    counts = (int*)p;    p += 64;

  hipMemsetAsync(deg, 0, (size_t)NPAD * 4, stream);
  hipMemsetAsync(cursor, 0, (size_t)NPAD * 4, stream);  // tail stays 0 -> empty segments for pad nodes
  hipMemsetAsync(pooled, 0, (size_t)NBATCH * H * 4, stream);
  hipMemsetAsync(counts, 0, 64, stream);

  p1_kernel<<<P1_B, 256, 0, stream>>>(x, Wn, bn, hb, ei, deg, mW1, ZW, mb1, We,
                                      be, WefS, bm, uW1, mW2, mb2, Wu, va);
  k2_kernel<<<K2_B, 256, 0, stream>>>(deg, bsum, Wu, uW2, WnS, bat, counts);
  scan3_kernel<<<NSB, 256, 0, stream>>>(deg, bsum, cursor);
  scatter_kernel<<<(NE + 255) / 256, 256, 0, stream>>>(ei, cursor, srcSrt, ea,
                                                       eaSrt);

  for (int l = 0; l < NLAYERS; ++l) {
    zz_kernel<<<ZZ_B, 256, 0, stream>>>(
        hb, ZW + (size_t)l * 8 * ZW_CHUNK, bm + (size_t)l * H, z,
        eaSrt, WefS + (size_t)l * CHUNK_ELEMS, zePre);
    edge_aggr_kernel<<<NPAD / 4, 256, 0, stream>>>(
        z, srcSrt, cursor, zePre, aggrB);
    node_update_mfma_kernel<<<NPAD / 64, 256, 0, stream>>>(
        hb, aggrB, deg, WnS + (size_t)l * NODE_CHUNKS * CHUNK_ELEMS,
        ub1 + (size_t)l * H, va + (size_t)l * H, ub2 + (size_t)l * H,
        bat, pooled, (l == NLAYERS - 1) ? 1 : 0);
  }

  readout_kernel<<<NBATCH, 128, 0, stream>>>(pooled, counts, gf, Wg, bg, rW1,
                                             rb1, rW2, rb2, rW3, rb3,
                                             (float*)d_out);
}

// Round 11
// 518.871 us; speedup vs baseline: 2.0728x; 2.0728x over previous
//
#include <hip/hip_runtime.h>

#define NN 50000
#define NPAD 50048     // 391 * 128
#define NE 400000
#define NBATCH 8
#define NDIM 32
#define EDIM 16
#define H 128
#define NLAYERS 3
#define CHUNK_ELEMS 4096   // node-kernel weight chunk: 2 hilo * 4 nt * 64 lane * 8
#define NODE_CHUNKS 24     // 16 (Wu, K=256) + 8 (uW2, K=128)
#define ZW_CHUNK 8192      // zdzs chunk: 2 hilo * 8 nt * 64 lane * 8
#define NSB 196            // scan blocks: ceil(50000/256)
#define ZEB 128            // edges per block in ze path (4 waves x 32)

// fused-grid block counts
#define EMB_B 1563                     // embed: 32 nodes/block
#define DEG_B 1563                     // degree: 256 edges/block
#define ZWB (NLAYERS * 8)              // 24
#define WEFB NLAYERS                   // 3 (wef + fused wefs swizzle)
#define WUB (NLAYERS * 257)            // 771
#define P1_B (EMB_B + DEG_B + ZWB + WEFB + WUB)   // 3924
#define K2_B (NSB + NLAYERS * NODE_CHUNKS + NSB)  // 464 (scan1 | wns | counts)
#define ZDZS_B (NPAD / 64)             // 782
#define ZE_B (NE / ZEB)                // 3125
#define ZZ_B (ZDZS_B + ZE_B)           // 3907

typedef __attribute__((ext_vector_type(8))) __bf16 bf16x8;
typedef __attribute__((ext_vector_type(16))) float f32x16;
typedef __attribute__((ext_vector_type(8))) short short8;
typedef __attribute__((ext_vector_type(2))) float v2f;

__device__ __forceinline__ void block_sync_lds() {
  asm volatile("s_waitcnt lgkmcnt(0)\ns_barrier" ::: "memory");
}
// one dword = 2 packed bf16 -> 2 fp32 (pure bit ops)
__device__ __forceinline__ v2f bf2f(unsigned u) {
  v2f r;
  r.x = __uint_as_float(u << 16);
  r.y = __uint_as_float(u & 0xffff0000u);
  return r;
}

// ================= P1: embed | degree | precomp_zw | precomp_wef(+wefs) | precomp_wu ===
__global__ __launch_bounds__(256) void p1_kernel(
    const float* __restrict__ x, const float* __restrict__ Wn,
    const float* __restrict__ bn, __bf16* __restrict__ hb,
    const int* __restrict__ ei, int* __restrict__ deg,
    const float* __restrict__ mW1, __bf16* __restrict__ ZW,
    const float* __restrict__ mb1, const float* __restrict__ We,
    const float* __restrict__ be, __bf16* __restrict__ WefS,
    float* __restrict__ bm, const float* __restrict__ uW1,
    const float* __restrict__ mW2, const float* __restrict__ mb2,
    float* __restrict__ Wu, float* __restrict__ va) {
  __shared__ __align__(16) float smem[NDIM * H + 32 * NDIM];  // 20 KB
  int bi = blockIdx.x;
  int tid = threadIdx.x;
  if (bi < EMB_B) {
    // ---- embed: h = x @ Wn + bn, 32 nodes/block ----
    float* Ws = smem;
    float* xs = smem + NDIM * H;
    int nbase = bi * 32;
    for (int f = tid; f < NDIM * H; f += 256) Ws[f] = Wn[f];
    for (int f = tid; f < 32 * NDIM; f += 256) {
      int gi = nbase * NDIM + f;
      xs[f] = (gi < NN * NDIM) ? x[gi] : 0.f;
    }
    __syncthreads();
    int j = tid & 127, g = tid >> 7;
    float wcol[NDIM];
#pragma unroll
    for (int k = 0; k < NDIM; ++k) wcol[k] = Ws[k * H + j];
    float b = bn[j];
    for (int nn = 0; nn < 16; ++nn) {
      int node = nbase + g * 16 + nn;
      if (node < NN) {
        float acc = b;
        const float4* xv = (const float4*)&xs[(g * 16 + nn) * NDIM];
#pragma unroll
        for (int k4 = 0; k4 < NDIM / 4; ++k4) {
          float4 v = xv[k4];
          acc = fmaf(v.x, wcol[k4 * 4 + 0], acc);
          acc = fmaf(v.y, wcol[k4 * 4 + 1], acc);
          acc = fmaf(v.z, wcol[k4 * 4 + 2], acc);
          acc = fmaf(v.w, wcol[k4 * 4 + 3], acc);
        }
        hb[(size_t)node * H + j] = (__bf16)acc;
      }
    }
  } else if (bi < EMB_B + DEG_B) {
    // ---- degree histogram over dst ----
    int e = (bi - EMB_B) * 256 + tid;
    if (e < NE) atomicAdd(&deg[ei[NE + e]], 1);
  } else if (bi < EMB_B + DEG_B + ZWB) {
    // ---- zdzs weights: mW1[0:256] -> hi/lo bf16, frag-swizzled ----
    int bb = bi - EMB_B - DEG_B;
    int l = bb / 8;
    int c = bb % 8;
    const float* w1 = mW1 + (size_t)l * 384 * H;
    __bf16* dst = ZW + ((size_t)l * 8 + c) * ZW_CHUNK;
    for (int it = 0; it < 32; it += 4) {
      float wv[4];
#pragma unroll
      for (int q = 0; q < 4; ++q) {
        int flat = (it + q) * 256 + tid;
        int j = flat & 7;
        int lane = (flat >> 3) & 63;
        int nt = (flat >> 9) & 7;
        int k = c * 16 + ((lane >> 5) << 3) + j;
        int n = nt * 32 + (lane & 31);
        wv[q] = (n < 128) ? w1[(size_t)k * H + n]
                          : w1[(size_t)(128 + k) * H + (n - 128)];
      }
#pragma unroll
      for (int q = 0; q < 4; ++q) {
        int flat = (it + q) * 256 + tid;
        int hilo = flat >> 12;
        __bf16 hi = (__bf16)wv[q];
        __bf16 lo = (__bf16)(wv[q] - (float)hi);
        dst[flat] = hilo ? lo : hi;
      }
    }
  } else if (bi < EMB_B + DEG_B + ZWB + WEFB) {
    // ---- Wef = We @ mW1[256:384] -> swizzled WefS directly (LDS transpose) ----
    int l = bi - (EMB_B + DEG_B + ZWB);
    float* WeS = smem;            // 2048
    float* beS = smem + 2048;     // 128
    float* wefT = smem + 2176;    // 2048: Wef[k][n] transpose buffer
    for (int f = tid; f < EDIM * H; f += 256) WeS[f] = We[f];
    if (tid < 128) beS[tid] = be[tid];
    __syncthreads();
    if (tid < 128) {
      int n = tid;
      const float* w1 = mW1 + (size_t)l * 384 * H + (size_t)256 * H + n;
      float acc[EDIM];
#pragma unroll
      for (int i = 0; i < EDIM; ++i) acc[i] = 0.f;
      float accb = 0.f;
      for (int c = 0; c < H; c += 4) {
        float w0 = w1[(size_t)(c + 0) * H];
        float w1v = w1[(size_t)(c + 1) * H];
        float w2 = w1[(size_t)(c + 2) * H];
        float w3 = w1[(size_t)(c + 3) * H];
        accb = fmaf(beS[c + 0], w0, accb);
        accb = fmaf(beS[c + 1], w1v, accb);
        accb = fmaf(beS[c + 2], w2, accb);
        accb = fmaf(beS[c + 3], w3, accb);
#pragma unroll
        for (int i = 0; i < EDIM; ++i) {
          acc[i] = fmaf(WeS[i * H + c + 0], w0, acc[i]);
          acc[i] = fmaf(WeS[i * H + c + 1], w1v, acc[i]);
          acc[i] = fmaf(WeS[i * H + c + 2], w2, acc[i]);
          acc[i] = fmaf(WeS[i * H + c + 3], w3, acc[i]);
        }
      }
#pragma unroll
      for (int i = 0; i < EDIM; ++i) wefT[i * H + n] = acc[i];
      bm[l * H + n] = mb1[l * H + n] + accb;
    }
    __syncthreads();
    {
      int nt = tid >> 6, lane = tid & 63;
      int n = nt * 32 + (lane & 31);
      int half = lane >> 5;
      __bf16* dst = WefS + (size_t)l * CHUNK_ELEMS;
#pragma unroll
      for (int j = 0; j < 8; ++j) {
        int k = half * 8 + j;
        float w = wefT[k * H + n];
        __bf16 hi = (__bf16)w;
        __bf16 lo = (__bf16)(w - (float)hi);
        dst[((0 * 4 + nt) * 64 + lane) * 8 + j] = hi;
        dst[((1 * 4 + nt) * 64 + lane) * 8 + j] = lo;
      }
    }
  } else {
    // ---- folded update weights (fp32 Wu / va): half-split K, LDS row ----
    int bb = bi - (EMB_B + DEG_B + ZWB + WEFB);
    int l = bb / 257;
    int r = bb % 257;
    int j = tid & 127, hf = tid >> 7;
    const float* u1 = uW1 + (size_t)l * 256 * H;
    if (r < 128) {
      if (tid < 128) Wu[((size_t)l * 256 + r) * H + j] = u1[(size_t)r * H + j];
    } else {
      float* rowS = smem;        // 128: broadcast row
      float* redS = smem + 128;  // 128: cross-half partial
      if (tid < 128)
        rowS[tid] = (r < 256) ? mW2[((size_t)l * H + (r - 128)) * H + tid]
                              : mb2[l * H + tid];
      __syncthreads();
      int cb = hf * 64;
      float s0 = 0.f, s1 = 0.f, s2 = 0.f, s3 = 0.f;
      for (int c = 0; c < 64; c += 4) {
        float a0 = u1[(size_t)(128 + cb + c + 0) * H + j];
        float a1 = u1[(size_t)(128 + cb + c + 1) * H + j];
        float a2 = u1[(size_t)(128 + cb + c + 2) * H + j];
        float a3 = u1[(size_t)(128 + cb + c + 3) * H + j];
        s0 = fmaf(rowS[cb + c + 0], a0, s0);
        s1 = fmaf(rowS[cb + c + 1], a1, s1);
        s2 = fmaf(rowS[cb + c + 2], a2, s2);
        s3 = fmaf(rowS[cb + c + 3], a3, s3);
      }
      float s = (s0 + s1) + (s2 + s3);
      if (hf == 1) redS[j] = s;
      __syncthreads();
      if (hf == 0) {
        float tot = s + redS[j];
        if (r < 256) Wu[((size_t)l * 256 + r) * H + j] = tot;
        else va[l * H + j] = tot;
      }
    }
  }
}

// ================= K2: scan1 | precomp_wns | batch counts ===
// counts branch: LDS histogram first, <=8 global atomics per block (the R10
// per-thread global-atomic version serialized 50000 RMWs on ONE cache line
// -> 571 us. Guideline 12.)
__global__ __launch_bounds__(256) void k2_kernel(
    const int* __restrict__ deg, int* __restrict__ bsum,
    const float* __restrict__ Wu, const float* __restrict__ uW2,
    __bf16* __restrict__ WnS, const int* __restrict__ batch,
    int* __restrict__ counts) {
  __shared__ int ws[4];
  __shared__ int cS[NBATCH];
  int bi = blockIdx.x;
  int tid = threadIdx.x;
  if (bi < NSB) {
    // ---- scan1: per-block degree sums ----
    int i = bi * 256 + tid;
    int lane = tid & 63, wid = tid >> 6;
    int v = (i < NN) ? deg[i] : 0;
#pragma unroll
    for (int off = 32; off; off >>= 1) v += __shfl_down(v, off);
    if (lane == 0) ws[wid] = v;
    __syncthreads();
    if (tid == 0) bsum[bi] = ws[0] + ws[1] + ws[2] + ws[3];
  } else if (bi < NSB + NLAYERS * NODE_CHUNKS) {
    // ---- swizzle node weights into hi/lo frag chunks ----
    int idx = bi - NSB;
    int l = idx / NODE_CHUNKS;
    int c = idx % NODE_CHUNKS;
    int nt = tid >> 6, lane = tid & 63;
    int n = nt * 32 + (lane & 31);
    int half = lane >> 5;
    __bf16* dst = WnS + ((size_t)l * NODE_CHUNKS + c) * CHUNK_ELEMS;
#pragma unroll
    for (int j = 0; j < 8; ++j) {
      float w;
      if (c < 16) {
        int k = c * 16 + half * 8 + j;
        w = Wu[((size_t)l * 256 + k) * H + n];
      } else {
        int k = (c - 16) * 16 + half * 8 + j;
        w = uW2[((size_t)l * H + k) * H + n];
      }
      __bf16 hi = (__bf16)w;
      __bf16 lo = (__bf16)(w - (float)hi);
      dst[((0 * 4 + nt) * 64 + lane) * 8 + j] = hi;
      dst[((1 * 4 + nt) * 64 + lane) * 8 + j] = lo;
    }
  } else {
    // ---- batch counts: LDS histogram -> <=8 global atomics/block ----
    if (tid < NBATCH) cS[tid] = 0;
    __syncthreads();
    int i = (bi - NSB - NLAYERS * NODE_CHUNKS) * 256 + tid;
    if (i < NN) atomicAdd(&cS[batch[i]], 1);
    __syncthreads();
    if (tid < NBATCH) {
      int v = cS[tid];
      if (v) atomicAdd(&counts[tid], v);
    }
  }
}

// ---------------- scan3 (with scan2 folded in: each block scans bsum locally) ----
__global__ __launch_bounds__(256) void scan3_kernel(const int* __restrict__ deg,
                                                    const int* __restrict__ bsum,
                                                    int* __restrict__ cursor) {
  __shared__ int s[256];
  __shared__ int wsum[4], woff[4];
  int t = threadIdx.x;
  int bv = (t < NSB) ? bsum[t] : 0;
  s[t] = bv;
  __syncthreads();
  for (int off = 1; off < 256; off <<= 1) {
    int u = (t >= off) ? s[t - off] : 0;
    __syncthreads();
    s[t] += u;
    __syncthreads();
  }
  int boff_b = s[blockIdx.x] - bsum[blockIdx.x];  // exclusive prefix for this block
  __syncthreads();

  int i = blockIdx.x * 256 + t;
  int lane = t & 63, wid = t >> 6;
  int orig = (i < NN) ? deg[i] : 0;
  int v = orig;
#pragma unroll
  for (int off = 1; off < 64; off <<= 1) {
    int u = __shfl_up(v, off);
    if (lane >= off) v += u;
  }
  if (lane == 63) wsum[wid] = v;
  __syncthreads();
  if (t == 0) {
    int r = 0;
#pragma unroll
    for (int w = 0; w < 4; ++w) {
      woff[w] = r;
      r += wsum[w];
    }
  }
  __syncthreads();
  if (i < NN) cursor[i] = (v - orig) + woff[wid] + boff_b;
}

// ---------------- counting-sort scatter + ea gather fused ----------------
__global__ __launch_bounds__(256) void scatter_kernel(
    const int* __restrict__ ei, int* __restrict__ cursor,
    int* __restrict__ srcSrt, const float* __restrict__ ea,
    __bf16* __restrict__ eaSrt) {
  int e = blockIdx.x * 256 + threadIdx.x;
  if (e < NE) {
    int d = ei[NE + e];
    int s = ei[e];
    const float4* ep = (const float4*)(ea + (size_t)e * EDIM);
    float4 v0 = ep[0], v1 = ep[1], v2 = ep[2], v3 = ep[3];
    int pos = atomicAdd(&cursor[d], 1);
    srcSrt[pos] = s;
    union { __bf16 b[16]; uint4 u[2]; } pk;
    pk.b[0] = (__bf16)v0.x;  pk.b[1] = (__bf16)v0.y;
    pk.b[2] = (__bf16)v0.z;  pk.b[3] = (__bf16)v0.w;
    pk.b[4] = (__bf16)v1.x;  pk.b[5] = (__bf16)v1.y;
    pk.b[6] = (__bf16)v1.z;  pk.b[7] = (__bf16)v1.w;
    pk.b[8] = (__bf16)v2.x;  pk.b[9] = (__bf16)v2.y;
    pk.b[10] = (__bf16)v2.z; pk.b[11] = (__bf16)v2.w;
    pk.b[12] = (__bf16)v3.x; pk.b[13] = (__bf16)v3.y;
    pk.b[14] = (__bf16)v3.z; pk.b[15] = (__bf16)v3.w;
    uint4* op = (uint4*)(eaSrt + (size_t)pos * EDIM);
    op[0] = pk.u[0];
    op[1] = pk.u[1];
  }
}

// ================= ZZ: zdzs (782 blocks) | ze (3125 blocks), one dispatch =====
__global__ __launch_bounds__(256) void zz_kernel(
    const __bf16* __restrict__ hb, const __bf16* __restrict__ ZW,
    const float* __restrict__ bm, __bf16* __restrict__ z,
    const __bf16* __restrict__ eaSrt, const __bf16* __restrict__ WefS,
    __bf16* __restrict__ zePre) {
  __shared__ __align__(16) __bf16 Bt[2][ZW_CHUNK];  // 32 KB
  int bi = blockIdx.x;
  int tid = threadIdx.x;
  int wid = tid >> 6, lane = tid & 63, m = lane & 31, half = lane >> 5;
  if (bi < ZDZS_B) {
    // ---- zdzs: z = h @ [W_d|W_s] (+bm on dst half), 64 rows/block ----
    int rg = wid & 1;   // 32-row group
    int nh = wid >> 1;  // nt quad
    int nb = bi * 64;
    int row = nb + rg * 32 + m;
    const __bf16* aH = hb + (size_t)row * H + half * 8;
    const short8* gW = (const short8*)ZW;  // 1024 short8 per chunk
    short8* sB0 = (short8*)&Bt[0][0];
    short8* sB1 = (short8*)&Bt[1][0];
#pragma unroll
    for (int q = 0; q < 4; ++q) sB0[tid + q * 256] = gW[tid + q * 256];
    short8 p0 = gW[1024 + tid], p1 = gW[1024 + tid + 256];
    short8 p2 = gW[1024 + tid + 512], p3 = gW[1024 + tid + 768];
    f32x16 acc[4];
#pragma unroll
    for (int ntl = 0; ntl < 4; ++ntl)
#pragma unroll
      for (int r = 0; r < 16; ++r) acc[ntl][r] = 0.f;
    bf16x8 a = *(const bf16x8*)aH;
    block_sync_lds();

    for (int s = 0; s < 8; ++s) {
      int buf = s & 1;
      bf16x8 na = a;
      if (s + 1 < 8) na = *(const bf16x8*)(aH + (s + 1) * 16);
      if (s + 1 < 8) {
        short8* sb = buf ? sB0 : sB1;
        sb[tid] = p0;
        sb[tid + 256] = p1;
        sb[tid + 512] = p2;
        sb[tid + 768] = p3;
        if (s + 2 < 8) {
          p0 = gW[(size_t)(s + 2) * 1024 + tid];
          p1 = gW[(size_t)(s + 2) * 1024 + tid + 256];
          p2 = gW[(size_t)(s + 2) * 1024 + tid + 512];
          p3 = gW[(size_t)(s + 2) * 1024 + tid + 768];
        }
      }
      const __bf16* bb = &Bt[buf][0];
#pragma unroll
      for (int ntl = 0; ntl < 4; ++ntl) {
        int nt = nh * 4 + ntl;
        bf16x8 bh = *(const bf16x8*)&bb[((0 * 8 + nt) * 64 + lane) * 8];
        bf16x8 bl = *(const bf16x8*)&bb[((1 * 8 + nt) * 64 + lane) * 8];
        acc[ntl] = __builtin_amdgcn_mfma_f32_32x32x16_bf16(a, bh, acc[ntl], 0, 0, 0);
        acc[ntl] = __builtin_amdgcn_mfma_f32_32x32x16_bf16(a, bl, acc[ntl], 0, 0, 0);
      }
      a = na;
      if (s + 1 < 8) block_sync_lds();
    }

    float bmv[4];
#pragma unroll
    for (int ntl = 0; ntl < 4; ++ntl) {
      int nt = nh * 4 + ntl;
      bmv[ntl] = (nt < 4) ? bm[nt * 32 + m] : 0.f;
    }
#pragma unroll
    for (int ntl = 0; ntl < 4; ++ntl) {
      int nt = nh * 4 + ntl;
#pragma unroll
      for (int r = 0; r < 16; ++r) {
        int rowi = (r & 3) + 8 * (r >> 2) + 4 * half;
        z[(size_t)(nb + rg * 32 + rowi) * 256 + nt * 32 + m] =
            (__bf16)(acc[ntl][r] + bmv[ntl]);
      }
    }
  } else {
    // ---- ze: zePre[e] = eaSrt[e] @ Wef, MFMA K=16 ----
    __bf16* Bf = &Bt[0][0];
    ((short8*)Bf)[tid] = ((const short8*)WefS)[tid];
    ((short8*)Bf)[tid + 256] = ((const short8*)WefS)[tid + 256];
    int ebase = (bi - ZDZS_B) * ZEB + wid * 32;
    bf16x8 a = *(const bf16x8*)(eaSrt + (size_t)(ebase + m) * EDIM + half * 8);
    f32x16 acc[4];
#pragma unroll
    for (int nt = 0; nt < 4; ++nt)
#pragma unroll
      for (int r = 0; r < 16; ++r) acc[nt][r] = 0.f;
    block_sync_lds();
#pragma unroll
    for (int nt = 0; nt < 4; ++nt) {
      bf16x8 bh = *(const bf16x8*)&Bf[((0 * 4 + nt) * 64 + lane) * 8];
      bf16x8 bl = *(const bf16x8*)&Bf[((1 * 4 + nt) * 64 + lane) * 8];
      acc[nt] = __builtin_amdgcn_mfma_f32_32x32x16_bf16(a, bh, acc[nt], 0, 0, 0);
      acc[nt] = __builtin_amdgcn_mfma_f32_32x32x16_bf16(a, bl, acc[nt], 0, 0, 0);
    }
#pragma unroll
    for (int nt = 0; nt < 4; ++nt) {
#pragma unroll
      for (int r = 0; r < 16; ++r) {
        int rowi = (r & 3) + 8 * (r >> 2) + 4 * half;
        zePre[(size_t)(ebase + rowi) * H + nt * 32 + m] = (__bf16)acc[nt][r];
      }
    }
  }
}

// ---------------- node-parallel CSR aggregation: aggr[n] = sum relu(zd+zs+ze) ----
// 8-deep gather batches (avg degree 8 -> one L3-latency wait per node).
__global__ __launch_bounds__(256) void edge_aggr_kernel(
    const __bf16* __restrict__ z, const int* __restrict__ srcSrt,
    const int* __restrict__ cend, const __bf16* __restrict__ zePre,
    __bf16* __restrict__ aggrB) {
  int node = blockIdx.x * 4 + (threadIdx.x >> 6);
  int lane = threadIdx.x & 63;
  int c0 = lane * 2;
  int end = cend[node];
  int start = node ? cend[node - 1] : 0;
  v2f acc = {0.f, 0.f};
  if (start < end) {
    v2f zd = bf2f(*(const unsigned*)(z + (size_t)node * 256 + c0));
    int sArr[8];
#pragma unroll
    for (int p = 0; p < 8; ++p)
      if (start + p < end) sArr[p] = srcSrt[start + p];
    for (int e0 = start; e0 < end; e0 += 8) {
      unsigned zsb[8], zeb[8];
#pragma unroll
      for (int p = 0; p < 8; ++p) {
        if (e0 + p < end) {
          zsb[p] = *(const unsigned*)(z + (size_t)sArr[p] * 256 + 128 + c0);
          zeb[p] = *(const unsigned*)(zePre + (size_t)(e0 + p) * H + c0);
        }
      }
#pragma unroll
      for (int p = 0; p < 8; ++p)
        if (e0 + 8 + p < end) sArr[p] = srcSrt[e0 + 8 + p];
#pragma unroll
      for (int p = 0; p < 8; ++p) {
        if (e0 + p < end) {
          v2f t = zd + bf2f(zsb[p]) + bf2f(zeb[p]);
          acc.x += fmaxf(t.x, 0.f);
          acc.y += fmaxf(t.y, 0.f);
        }
      }
    }
  }
  union { __bf16 b[2]; unsigned u; } pk;
  pk.b[0] = (__bf16)acc.x;
  pk.b[1] = (__bf16)acc.y;
  *(unsigned*)(aggrB + (size_t)node * H + c0) = pk.u;
}

// ---------------- MFMA fused node update (h bf16), 64 rows/block --------------
// doPool (last layer): mean-pool fused into the epilogue.
__global__ __launch_bounds__(256) void node_update_mfma_kernel(
    __bf16* __restrict__ hb, const __bf16* __restrict__ aggrB,
    const int* __restrict__ deg, const __bf16* __restrict__ WnS,
    const float* __restrict__ ub1, const float* __restrict__ va,
    const float* __restrict__ ub2, const int* __restrict__ batch,
    float* __restrict__ pooled, int doPool) {
  __shared__ __align__(16) __bf16 Bt[2][CHUNK_ELEMS];  // 16 KB
  __shared__ __bf16 hid[2][32][132];                   // 16.9 KB
  __shared__ float degS[64];
  int tid = threadIdx.x;
  int nb = blockIdx.x * 64;
  if (tid < 64) degS[tid] = (float)deg[nb + tid];
  int wid = tid >> 6, lane = tid & 63, m = lane & 31, half = lane >> 5;
  int rg = wid & 1;        // row group (32 rows)
  int nh = wid >> 1;       // col half (2 nt slots)
  int row = nb + rg * 32 + m;
  const __bf16* aHb = hb + (size_t)row * H + half * 8;
  const __bf16* aGb = aggrB + (size_t)row * H + half * 8;
  const short8* gW = (const short8*)WnS;
  short8* sB0 = (short8*)&Bt[0][0];
  short8* sB1 = (short8*)&Bt[1][0];
  sB0[tid] = gW[tid];
  sB0[tid + 256] = gW[tid + 256];
  short8 p0 = gW[512 + tid], p1 = gW[512 + tid + 256];
  float bv1[2], bva[2];
#pragma unroll
  for (int ntl = 0; ntl < 2; ++ntl) {
    int nt = nh * 2 + ntl;
    bv1[ntl] = ub1[nt * 32 + m];
    bva[ntl] = va[nt * 32 + m];
  }
  f32x16 acc[2];
#pragma unroll
  for (int ntl = 0; ntl < 2; ++ntl)
#pragma unroll
    for (int r = 0; r < 16; ++r) acc[ntl][r] = 0.f;
  bf16x8 acur = *(const bf16x8*)aHb;
  block_sync_lds();

  for (int s = 0; s < 16; ++s) {
    int buf = s & 1;
    bf16x8 anext = acur;
    if (s + 1 < 16) {
      int sp = s + 1;
      anext = (sp < 8) ? *(const bf16x8*)(aHb + sp * 16)
                       : *(const bf16x8*)(aGb + (sp - 8) * 16);
    }
    {
      short8* sb = buf ? sB0 : sB1;
      sb[tid] = p0;
      sb[tid + 256] = p1;
      if (s + 2 < NODE_CHUNKS) {
        p0 = gW[(size_t)(s + 2) * 512 + tid];
        p1 = gW[(size_t)(s + 2) * 512 + tid + 256];
      }
    }
    const __bf16* bb = &Bt[buf][0];
#pragma unroll
    for (int ntl = 0; ntl < 2; ++ntl) {
      int nt = nh * 2 + ntl;
      bf16x8 bh = *(const bf16x8*)&bb[((0 * 4 + nt) * 64 + lane) * 8];
      bf16x8 bl = *(const bf16x8*)&bb[((1 * 4 + nt) * 64 + lane) * 8];
      acc[ntl] = __builtin_amdgcn_mfma_f32_32x32x16_bf16(acur, bh, acc[ntl], 0, 0, 0);
      acc[ntl] = __builtin_amdgcn_mfma_f32_32x32x16_bf16(acur, bl, acc[ntl], 0, 0, 0);
    }
    acur = anext;
    block_sync_lds();
  }

#pragma unroll
  for (int ntl = 0; ntl < 2; ++ntl) {
    int nt = nh * 2 + ntl;
#pragma unroll
    for (int r = 0; r < 16; ++r) {
      int rowi = (r & 3) + 8 * (r >> 2) + 4 * half;
      float v = acc[ntl][r] + bv1[ntl] + degS[rg * 32 + rowi] * bva[ntl];
      hid[rg][rowi][nt * 32 + m] = (__bf16)fmaxf(v, 0.f);
      acc[ntl][r] = 0.f;
    }
  }
  // hid cols are split across the two nh waves of each row group ->
  // full barrier before any wave reads hid.
  block_sync_lds();

  for (int s = 16; s < NODE_CHUNKS; ++s) {
    int buf = s & 1;
    if (s + 1 < NODE_CHUNKS) {
      short8* sb = buf ? sB0 : sB1;
      sb[tid] = p0;
      sb[tid + 256] = p1;
      if (s + 2 < NODE_CHUNKS) {
        p0 = gW[(size_t)(s + 2) * 512 + tid];
        p1 = gW[(size_t)(s + 2) * 512 + tid + 256];
      }
    }
    bf16x8 ah = *(const bf16x8*)&hid[rg][m][(s - 16) * 16 + half * 8];
    const __bf16* bb = &Bt[buf][0];
#pragma unroll
    for (int ntl = 0; ntl < 2; ++ntl) {
      int nt = nh * 2 + ntl;
      bf16x8 bh = *(const bf16x8*)&bb[((0 * 4 + nt) * 64 + lane) * 8];
      bf16x8 bl = *(const bf16x8*)&bb[((1 * 4 + nt) * 64 + lane) * 8];
      acc[ntl] = __builtin_amdgcn_mfma_f32_32x32x16_bf16(ah, bh, acc[ntl], 0, 0, 0);
      acc[ntl] = __builtin_amdgcn_mfma_f32_32x32x16_bf16(ah, bl, acc[ntl], 0, 0, 0);
    }
    if (s + 1 < NODE_CHUNKS) block_sync_lds();
  }

  float* pS = (float*)&Bt[0][0];       // 1024 floats (4 KB), Bt dead now
  int* bS = (int*)&hid[0][0][0];       // 64 ints, hid dead now
  if (doPool) {
    block_sync_lds();  // all waves done reading Bt/hid
    if (tid < 64) bS[tid] = (nb + tid < NN) ? batch[nb + tid] : -1;
    for (int i = tid; i < NBATCH * H; i += 256) pS[i] = 0.f;
    block_sync_lds();
  }

#pragma unroll
  for (int ntl = 0; ntl < 2; ++ntl) {
    int nt = nh * 2 + ntl;
    float b2 = ub2[nt * 32 + m];
#pragma unroll
    for (int r = 0; r < 16; ++r) {
      int rowi = (r & 3) + 8 * (r >> 2) + 4 * half;
      int lr2 = rg * 32 + rowi;
      size_t idx = (size_t)(nb + lr2) * H + nt * 32 + m;
      float hv = (float)hb[idx];
      float val = hv + acc[ntl][r] + b2;
      hb[idx] = (__bf16)val;
      if (doPool) {
        int b = bS[lr2];
        if (b >= 0) {
          float pv = (float)(__bf16)val;  // match pooling of rounded bf16 h
          atomicAdd(&pS[b * H + nt * 32 + m], pv);
        }
      }
    }
  }

  if (doPool) {
    block_sync_lds();
    for (int i = tid; i < NBATCH * H; i += 256) {
      float v = pS[i];
      if (v != 0.f) unsafeAtomicAdd(&pooled[i], v);
    }
  }
}

// ---------------- readout MLP: one block per batch ----------------
__global__ __launch_bounds__(128) void readout_kernel(
    const float* __restrict__ pooled, const int* __restrict__ counts,
    const float* __restrict__ gf, const float* __restrict__ Wg,
    const float* __restrict__ bg, const float* __restrict__ rW1,
    const float* __restrict__ rb1, const float* __restrict__ rW2,
    const float* __restrict__ rb2, const float* __restrict__ rW3,
    const float* __restrict__ rb3, float* __restrict__ out) {
  __shared__ float fin[256];
  __shared__ float t1[128];
  __shared__ float t2[64];
  int j = threadIdx.x;
  int b = blockIdx.x;
  float cnt = (float)counts[b];
  if (cnt < 1.f) cnt = 1.f;
  fin[j] = pooled[b * H + j] / cnt;
  fin[H + j] = fmaf(gf[b], Wg[j], bg[j]);
  __syncthreads();
  float a = rb1[j];
  for (int k = 0; k < 256; ++k) a = fmaf(fin[k], rW1[k * H + j], a);
  t1[j] = fmaxf(a, 0.f);
  __syncthreads();
  if (j < 64) {
    float a2 = rb2[j];
    for (int k = 0; k < 128; ++k) a2 = fmaf(t1[k], rW2[k * 64 + j], a2);
    t2[j] = fmaxf(a2, 0.f);
  }
  __syncthreads();
  if (j < 64) {
    float p = t2[j] * rW3[j];
#pragma unroll
    for (int off = 32; off; off >>= 1) p += __shfl_down(p, off);
    if (j == 0) out[b] = p + rb3[0];
  }
}

extern "C" void kernel_launch(void* const* d_in, const int* in_sizes, int n_in,
                              void* d_out, int out_size, void* d_ws, size_t ws_size,
                              hipStream_t stream) {
  const float* x   = (const float*)d_in[0];
  const float* ea  = (const float*)d_in[1];
  const float* gf  = (const float*)d_in[2];
  const int*   ei  = (const int*)d_in[3];
  const int*   bat = (const int*)d_in[4];
  const float* Wn  = (const float*)d_in[5];
  const float* bn  = (const float*)d_in[6];
  const float* We  = (const float*)d_in[7];
  const float* be  = (const float*)d_in[8];
  const float* Wg  = (const float*)d_in[9];
  const float* bg  = (const float*)d_in[10];
  const float* mW1 = (const float*)d_in[11];
  const float* mb1 = (const float*)d_in[12];
  const float* mW2 = (const float*)d_in[13];
  const float* mb2 = (const float*)d_in[14];
  const float* uW1 = (const float*)d_in[15];
  const float* ub1 = (const float*)d_in[16];
  const float* uW2 = (const float*)d_in[17];
  const float* ub2 = (const float*)d_in[18];
  const float* rW1 = (const float*)d_in[19];
  const float* rb1 = (const float*)d_in[20];
  const float* rW2 = (const float*)d_in[21];
  const float* rb2 = (const float*)d_in[22];
  const float* rW3 = (const float*)d_in[23];
  const float* rb3 = (const float*)d_in[24];

  char* p = (char*)d_ws;
  __bf16* hb     = (__bf16*)p; p += (size_t)NPAD * H * 2;        // 12.8 MB
  __bf16* aggrB  = (__bf16*)p; p += (size_t)NPAD * H * 2;        // 12.8 MB
  __bf16* z      = (__bf16*)p; p += (size_t)NPAD * 256 * 2;      // 25.6 MB
  __bf16* zePre  = (__bf16*)p; p += (size_t)NE * H * 2;          // 102.4 MB
  __bf16* eaSrt  = (__bf16*)p; p += (size_t)NE * EDIM * 2;       // 12.8 MB
  int*    srcSrt = (int*)p;    p += (size_t)NE * 4;              // 1.6 MB
  __bf16* ZW     = (__bf16*)p; p += (size_t)NLAYERS * 8 * ZW_CHUNK * 2;
  __bf16* WnS    = (__bf16*)p; p += (size_t)NLAYERS * NODE_CHUNKS * CHUNK_ELEMS * 2;
  __bf16* WefS   = (__bf16*)p; p += (size_t)NLAYERS * CHUNK_ELEMS * 2;
  float*  bm     = (float*)p;  p += (size_t)NLAYERS * H * 4;
  float*  Wu     = (float*)p;  p += (size_t)NLAYERS * 256 * H * 4;
  float*  va     = (float*)p;  p += (size_t)NLAYERS * H * 4;
  int*    deg    = (int*)p;    p += (size_t)NPAD * 4;
  int*    cursor = (int*)p;    p += (size_t)NPAD * 4;
  int*    bsum   = (int*)p;    p += 256 * 4;
  float*  pooled = (float*)p;  p += (size_t)NBATCH * H * 4;
  int*    counts = (int*)p;    p += 64;

  hipMemsetAsync(deg, 0, (size_t)NPAD * 4, stream);
  hipMemsetAsync(cursor, 0, (size_t)NPAD * 4, stream);  // tail stays 0 -> empty segments for pad nodes
  hipMemsetAsync(pooled, 0, (size_t)NBATCH * H * 4, stream);
  hipMemsetAsync(counts, 0, 64, stream);

  p1_kernel<<<P1_B, 256, 0, stream>>>(x, Wn, bn, hb, ei, deg, mW1, ZW, mb1, We,
                                      be, WefS, bm, uW1, mW2, mb2, Wu, va);
  k2_kernel<<<K2_B, 256, 0, stream>>>(deg, bsum, Wu, uW2, WnS, bat, counts);
  scan3_kernel<<<NSB, 256, 0, stream>>>(deg, bsum, cursor);
  scatter_kernel<<<(NE + 255) / 256, 256, 0, stream>>>(ei, cursor, srcSrt, ea,
                                                       eaSrt);

  for (int l = 0; l < NLAYERS; ++l) {
    zz_kernel<<<ZZ_B, 256, 0, stream>>>(
        hb, ZW + (size_t)l * 8 * ZW_CHUNK, bm + (size_t)l * H, z,
        eaSrt, WefS + (size_t)l * CHUNK_ELEMS, zePre);
    edge_aggr_kernel<<<NPAD / 4, 256, 0, stream>>>(
        z, srcSrt, cursor, zePre, aggrB);
    node_update_mfma_kernel<<<NPAD / 64, 256, 0, stream>>>(
        hb, aggrB, deg, WnS + (size_t)l * NODE_CHUNKS * CHUNK_ELEMS,
        ub1 + (size_t)l * H, va + (size_t)l * H, ub2 + (size_t)l * H,
        bat, pooled, (l == NLAYERS - 1) ? 1 : 0);
  }

  readout_kernel<<<NBATCH, 128, 0, stream>>>(pooled, counts, gf, Wg, bg, rW1,
                                             rb1, rW2, rb2, rW3, rb3,
                                             (float*)d_out);
}

// Round 12
// 496.580 us; speedup vs baseline: 2.1658x; 1.0449x over previous
//
#include <hip/hip_runtime.h>

#define NN 50000
#define NPAD 50048     // 391 * 128
#define NE 400000
#define NBATCH 8
#define NDIM 32
#define EDIM 16
#define H 128
#define NLAYERS 3
#define CHUNK_ELEMS 4096   // node-kernel weight chunk: 2 hilo * 4 nt * 64 lane * 8
#define NODE_CHUNKS 24     // 16 (Wu, K=256) + 8 (uW2, K=128)
#define ZW_CHUNK 8192      // zdzs chunk: 2 hilo * 8 nt * 64 lane * 8
#define NSB 196            // scan blocks: ceil(50000/256)
#define ZEB 128            // edges per block in ze path (4 waves x 32)

// fused-grid block counts
#define EMB_B 1563                     // embed: 32 nodes/block
#define DEG_B 1563                     // degree: 256 edges/block
#define ZWB (NLAYERS * 8)              // 24
#define WEFB NLAYERS                   // 3 (wef + fused wefs swizzle)
#define WUB (NLAYERS * 257)            // 771
#define P1_B (EMB_B + DEG_B + ZWB + WEFB + WUB)   // 3924
#define K2_B (NSB + NLAYERS * NODE_CHUNKS)        // 268 (scan1 | wns)
#define ZDZS_B (NPAD / 64)             // 782
#define ZE_B (NE / ZEB)                // 3125
#define ZZ_B (ZDZS_B + ZE_B)           // 3907

typedef __attribute__((ext_vector_type(8))) __bf16 bf16x8;
typedef __attribute__((ext_vector_type(16))) float f32x16;
typedef __attribute__((ext_vector_type(8))) short short8;
typedef __attribute__((ext_vector_type(2))) float v2f;

__device__ __forceinline__ void block_sync_lds() {
  asm volatile("s_waitcnt lgkmcnt(0)\ns_barrier" ::: "memory");
}
// one dword = 2 packed bf16 -> 2 fp32 (pure bit ops)
__device__ __forceinline__ v2f bf2f(unsigned u) {
  v2f r;
  r.x = __uint_as_float(u << 16);
  r.y = __uint_as_float(u & 0xffff0000u);
  return r;
}

// ================= P1: embed | degree | precomp_zw | precomp_wef(+wefs) | precomp_wu ===
__global__ __launch_bounds__(256) void p1_kernel(
    const float* __restrict__ x, const float* __restrict__ Wn,
    const float* __restrict__ bn, __bf16* __restrict__ hb,
    const int* __restrict__ ei, int* __restrict__ deg,
    const float* __restrict__ mW1, __bf16* __restrict__ ZW,
    const float* __restrict__ mb1, const float* __restrict__ We,
    const float* __restrict__ be, __bf16* __restrict__ WefS,
    float* __restrict__ bm, const float* __restrict__ uW1,
    const float* __restrict__ mW2, const float* __restrict__ mb2,
    float* __restrict__ Wu, float* __restrict__ va) {
  __shared__ __align__(16) float smem[NDIM * H + 32 * NDIM];  // 20 KB
  int bi = blockIdx.x;
  int tid = threadIdx.x;
  if (bi < EMB_B) {
    // ---- embed: h = x @ Wn + bn, 32 nodes/block ----
    float* Ws = smem;
    float* xs = smem + NDIM * H;
    int nbase = bi * 32;
    for (int f = tid; f < NDIM * H; f += 256) Ws[f] = Wn[f];
    for (int f = tid; f < 32 * NDIM; f += 256) {
      int gi = nbase * NDIM + f;
      xs[f] = (gi < NN * NDIM) ? x[gi] : 0.f;
    }
    __syncthreads();
    int j = tid & 127, g = tid >> 7;
    float wcol[NDIM];
#pragma unroll
    for (int k = 0; k < NDIM; ++k) wcol[k] = Ws[k * H + j];
    float b = bn[j];
    for (int nn = 0; nn < 16; ++nn) {
      int node = nbase + g * 16 + nn;
      if (node < NN) {
        float acc = b;
        const float4* xv = (const float4*)&xs[(g * 16 + nn) * NDIM];
#pragma unroll
        for (int k4 = 0; k4 < NDIM / 4; ++k4) {
          float4 v = xv[k4];
          acc = fmaf(v.x, wcol[k4 * 4 + 0], acc);
          acc = fmaf(v.y, wcol[k4 * 4 + 1], acc);
          acc = fmaf(v.z, wcol[k4 * 4 + 2], acc);
          acc = fmaf(v.w, wcol[k4 * 4 + 3], acc);
        }
        hb[(size_t)node * H + j] = (__bf16)acc;
      }
    }
  } else if (bi < EMB_B + DEG_B) {
    // ---- degree histogram over dst ----
    int e = (bi - EMB_B) * 256 + tid;
    if (e < NE) atomicAdd(&deg[ei[NE + e]], 1);
  } else if (bi < EMB_B + DEG_B + ZWB) {
    // ---- zdzs weights: mW1[0:256] -> hi/lo bf16, frag-swizzled ----
    int bb = bi - EMB_B - DEG_B;
    int l = bb / 8;
    int c = bb % 8;
    const float* w1 = mW1 + (size_t)l * 384 * H;
    __bf16* dst = ZW + ((size_t)l * 8 + c) * ZW_CHUNK;
    for (int it = 0; it < 32; it += 4) {
      float wv[4];
#pragma unroll
      for (int q = 0; q < 4; ++q) {
        int flat = (it + q) * 256 + tid;
        int j = flat & 7;
        int lane = (flat >> 3) & 63;
        int nt = (flat >> 9) & 7;
        int k = c * 16 + ((lane >> 5) << 3) + j;
        int n = nt * 32 + (lane & 31);
        wv[q] = (n < 128) ? w1[(size_t)k * H + n]
                          : w1[(size_t)(128 + k) * H + (n - 128)];
      }
#pragma unroll
      for (int q = 0; q < 4; ++q) {
        int flat = (it + q) * 256 + tid;
        int hilo = flat >> 12;
        __bf16 hi = (__bf16)wv[q];
        __bf16 lo = (__bf16)(wv[q] - (float)hi);
        dst[flat] = hilo ? lo : hi;
      }
    }
  } else if (bi < EMB_B + DEG_B + ZWB + WEFB) {
    // ---- Wef = We @ mW1[256:384] -> swizzled WefS directly (LDS transpose) ----
    int l = bi - (EMB_B + DEG_B + ZWB);
    float* WeS = smem;            // 2048
    float* beS = smem + 2048;     // 128
    float* wefT = smem + 2176;    // 2048: Wef[k][n] transpose buffer
    for (int f = tid; f < EDIM * H; f += 256) WeS[f] = We[f];
    if (tid < 128) beS[tid] = be[tid];
    __syncthreads();
    if (tid < 128) {
      int n = tid;
      const float* w1 = mW1 + (size_t)l * 384 * H + (size_t)256 * H + n;
      float acc[EDIM];
#pragma unroll
      for (int i = 0; i < EDIM; ++i) acc[i] = 0.f;
      float accb = 0.f;
      for (int c = 0; c < H; c += 4) {
        float w0 = w1[(size_t)(c + 0) * H];
        float w1v = w1[(size_t)(c + 1) * H];
        float w2 = w1[(size_t)(c + 2) * H];
        float w3 = w1[(size_t)(c + 3) * H];
        accb = fmaf(beS[c + 0], w0, accb);
        accb = fmaf(beS[c + 1], w1v, accb);
        accb = fmaf(beS[c + 2], w2, accb);
        accb = fmaf(beS[c + 3], w3, accb);
#pragma unroll
        for (int i = 0; i < EDIM; ++i) {
          acc[i] = fmaf(WeS[i * H + c + 0], w0, acc[i]);
          acc[i] = fmaf(WeS[i * H + c + 1], w1v, acc[i]);
          acc[i] = fmaf(WeS[i * H + c + 2], w2, acc[i]);
          acc[i] = fmaf(WeS[i * H + c + 3], w3, acc[i]);
        }
      }
#pragma unroll
      for (int i = 0; i < EDIM; ++i) wefT[i * H + n] = acc[i];
      bm[l * H + n] = mb1[l * H + n] + accb;
    }
    __syncthreads();
    {
      int nt = tid >> 6, lane = tid & 63;
      int n = nt * 32 + (lane & 31);
      int half = lane >> 5;
      __bf16* dst = WefS + (size_t)l * CHUNK_ELEMS;
#pragma unroll
      for (int j = 0; j < 8; ++j) {
        int k = half * 8 + j;
        float w = wefT[k * H + n];
        __bf16 hi = (__bf16)w;
        __bf16 lo = (__bf16)(w - (float)hi);
        dst[((0 * 4 + nt) * 64 + lane) * 8 + j] = hi;
        dst[((1 * 4 + nt) * 64 + lane) * 8 + j] = lo;
      }
    }
  } else {
    // ---- folded update weights (fp32 Wu / va): half-split K, LDS row ----
    int bb = bi - (EMB_B + DEG_B + ZWB + WEFB);
    int l = bb / 257;
    int r = bb % 257;
    int j = tid & 127, hf = tid >> 7;
    const float* u1 = uW1 + (size_t)l * 256 * H;
    if (r < 128) {
      if (tid < 128) Wu[((size_t)l * 256 + r) * H + j] = u1[(size_t)r * H + j];
    } else {
      float* rowS = smem;        // 128: broadcast row
      float* redS = smem + 128;  // 128: cross-half partial
      if (tid < 128)
        rowS[tid] = (r < 256) ? mW2[((size_t)l * H + (r - 128)) * H + tid]
                              : mb2[l * H + tid];
      __syncthreads();
      int cb = hf * 64;
      float s0 = 0.f, s1 = 0.f, s2 = 0.f, s3 = 0.f;
      for (int c = 0; c < 64; c += 4) {
        float a0 = u1[(size_t)(128 + cb + c + 0) * H + j];
        float a1 = u1[(size_t)(128 + cb + c + 1) * H + j];
        float a2 = u1[(size_t)(128 + cb + c + 2) * H + j];
        float a3 = u1[(size_t)(128 + cb + c + 3) * H + j];
        s0 = fmaf(rowS[cb + c + 0], a0, s0);
        s1 = fmaf(rowS[cb + c + 1], a1, s1);
        s2 = fmaf(rowS[cb + c + 2], a2, s2);
        s3 = fmaf(rowS[cb + c + 3], a3, s3);
      }
      float s = (s0 + s1) + (s2 + s3);
      if (hf == 1) redS[j] = s;
      __syncthreads();
      if (hf == 0) {
        float tot = s + redS[j];
        if (r < 256) Wu[((size_t)l * 256 + r) * H + j] = tot;
        else va[l * H + j] = tot;
      }
    }
  }
}

// ================= K2: scan1 | precomp_wns ===
__global__ __launch_bounds__(256) void k2_kernel(
    const int* __restrict__ deg, int* __restrict__ bsum,
    const float* __restrict__ Wu, const float* __restrict__ uW2,
    __bf16* __restrict__ WnS) {
  __shared__ int ws[4];
  int bi = blockIdx.x;
  int tid = threadIdx.x;
  if (bi < NSB) {
    // ---- scan1: per-block degree sums ----
    int i = bi * 256 + tid;
    int lane = tid & 63, wid = tid >> 6;
    int v = (i < NN) ? deg[i] : 0;
#pragma unroll
    for (int off = 32; off; off >>= 1) v += __shfl_down(v, off);
    if (lane == 0) ws[wid] = v;
    __syncthreads();
    if (tid == 0) bsum[bi] = ws[0] + ws[1] + ws[2] + ws[3];
  } else {
    // ---- swizzle node weights into hi/lo frag chunks ----
    int idx = bi - NSB;
    int l = idx / NODE_CHUNKS;
    int c = idx % NODE_CHUNKS;
    int nt = tid >> 6, lane = tid & 63;
    int n = nt * 32 + (lane & 31);
    int half = lane >> 5;
    __bf16* dst = WnS + ((size_t)l * NODE_CHUNKS + c) * CHUNK_ELEMS;
#pragma unroll
    for (int j = 0; j < 8; ++j) {
      float w;
      if (c < 16) {
        int k = c * 16 + half * 8 + j;
        w = Wu[((size_t)l * 256 + k) * H + n];
      } else {
        int k = (c - 16) * 16 + half * 8 + j;
        w = uW2[((size_t)l * H + k) * H + n];
      }
      __bf16 hi = (__bf16)w;
      __bf16 lo = (__bf16)(w - (float)hi);
      dst[((0 * 4 + nt) * 64 + lane) * 8 + j] = hi;
      dst[((1 * 4 + nt) * 64 + lane) * 8 + j] = lo;
    }
  }
}

// ---------------- scan3 (with scan2 folded in: each block scans bsum locally) ----
__global__ __launch_bounds__(256) void scan3_kernel(const int* __restrict__ deg,
                                                    const int* __restrict__ bsum,
                                                    int* __restrict__ cursor) {
  __shared__ int s[256];
  __shared__ int wsum[4], woff[4];
  int t = threadIdx.x;
  int bv = (t < NSB) ? bsum[t] : 0;
  s[t] = bv;
  __syncthreads();
  for (int off = 1; off < 256; off <<= 1) {
    int u = (t >= off) ? s[t - off] : 0;
    __syncthreads();
    s[t] += u;
    __syncthreads();
  }
  int boff_b = s[blockIdx.x] - bsum[blockIdx.x];  // exclusive prefix for this block
  __syncthreads();

  int i = blockIdx.x * 256 + t;
  int lane = t & 63, wid = t >> 6;
  int orig = (i < NN) ? deg[i] : 0;
  int v = orig;
#pragma unroll
  for (int off = 1; off < 64; off <<= 1) {
    int u = __shfl_up(v, off);
    if (lane >= off) v += u;
  }
  if (lane == 63) wsum[wid] = v;
  __syncthreads();
  if (t == 0) {
    int r = 0;
#pragma unroll
    for (int w = 0; w < 4; ++w) {
      woff[w] = r;
      r += wsum[w];
    }
  }
  __syncthreads();
  if (i < NN) cursor[i] = (v - orig) + woff[wid] + boff_b;
}

// ---------------- counting-sort scatter + ea gather fused ----------------
__global__ __launch_bounds__(256) void scatter_kernel(
    const int* __restrict__ ei, int* __restrict__ cursor,
    int* __restrict__ srcSrt, const float* __restrict__ ea,
    __bf16* __restrict__ eaSrt) {
  int e = blockIdx.x * 256 + threadIdx.x;
  if (e < NE) {
    int d = ei[NE + e];
    int s = ei[e];
    const float4* ep = (const float4*)(ea + (size_t)e * EDIM);
    float4 v0 = ep[0], v1 = ep[1], v2 = ep[2], v3 = ep[3];
    int pos = atomicAdd(&cursor[d], 1);
    srcSrt[pos] = s;
    union { __bf16 b[16]; uint4 u[2]; } pk;
    pk.b[0] = (__bf16)v0.x;  pk.b[1] = (__bf16)v0.y;
    pk.b[2] = (__bf16)v0.z;  pk.b[3] = (__bf16)v0.w;
    pk.b[4] = (__bf16)v1.x;  pk.b[5] = (__bf16)v1.y;
    pk.b[6] = (__bf16)v1.z;  pk.b[7] = (__bf16)v1.w;
    pk.b[8] = (__bf16)v2.x;  pk.b[9] = (__bf16)v2.y;
    pk.b[10] = (__bf16)v2.z; pk.b[11] = (__bf16)v2.w;
    pk.b[12] = (__bf16)v3.x; pk.b[13] = (__bf16)v3.y;
    pk.b[14] = (__bf16)v3.z; pk.b[15] = (__bf16)v3.w;
    uint4* op = (uint4*)(eaSrt + (size_t)pos * EDIM);
    op[0] = pk.u[0];
    op[1] = pk.u[1];
  }
}

// ================= ZZ: zdzs (782 blocks) | ze (3125 blocks), one dispatch =====
__global__ __launch_bounds__(256) void zz_kernel(
    const __bf16* __restrict__ hb, const __bf16* __restrict__ ZW,
    const float* __restrict__ bm, __bf16* __restrict__ z,
    const __bf16* __restrict__ eaSrt, const __bf16* __restrict__ WefS,
    __bf16* __restrict__ zePre) {
  __shared__ __align__(16) __bf16 Bt[2][ZW_CHUNK];  // 32 KB
  int bi = blockIdx.x;
  int tid = threadIdx.x;
  int wid = tid >> 6, lane = tid & 63, m = lane & 31, half = lane >> 5;
  if (bi < ZDZS_B) {
    // ---- zdzs: z = h @ [W_d|W_s] (+bm on dst half), 64 rows/block ----
    int rg = wid & 1;   // 32-row group
    int nh = wid >> 1;  // nt quad
    int nb = bi * 64;
    int row = nb + rg * 32 + m;
    const __bf16* aH = hb + (size_t)row * H + half * 8;
    const short8* gW = (const short8*)ZW;  // 1024 short8 per chunk
    short8* sB0 = (short8*)&Bt[0][0];
    short8* sB1 = (short8*)&Bt[1][0];
#pragma unroll
    for (int q = 0; q < 4; ++q) sB0[tid + q * 256] = gW[tid + q * 256];
    short8 p0 = gW[1024 + tid], p1 = gW[1024 + tid + 256];
    short8 p2 = gW[1024 + tid + 512], p3 = gW[1024 + tid + 768];
    f32x16 acc[4];
#pragma unroll
    for (int ntl = 0; ntl < 4; ++ntl)
#pragma unroll
      for (int r = 0; r < 16; ++r) acc[ntl][r] = 0.f;
    bf16x8 a = *(const bf16x8*)aH;
    block_sync_lds();

    for (int s = 0; s < 8; ++s) {
      int buf = s & 1;
      bf16x8 na = a;
      if (s + 1 < 8) na = *(const bf16x8*)(aH + (s + 1) * 16);
      if (s + 1 < 8) {
        short8* sb = buf ? sB0 : sB1;
        sb[tid] = p0;
        sb[tid + 256] = p1;
        sb[tid + 512] = p2;
        sb[tid + 768] = p3;
        if (s + 2 < 8) {
          p0 = gW[(size_t)(s + 2) * 1024 + tid];
          p1 = gW[(size_t)(s + 2) * 1024 + tid + 256];
          p2 = gW[(size_t)(s + 2) * 1024 + tid + 512];
          p3 = gW[(size_t)(s + 2) * 1024 + tid + 768];
        }
      }
      const __bf16* bb = &Bt[buf][0];
#pragma unroll
      for (int ntl = 0; ntl < 4; ++ntl) {
        int nt = nh * 4 + ntl;
        bf16x8 bh = *(const bf16x8*)&bb[((0 * 8 + nt) * 64 + lane) * 8];
        bf16x8 bl = *(const bf16x8*)&bb[((1 * 8 + nt) * 64 + lane) * 8];
        acc[ntl] = __builtin_amdgcn_mfma_f32_32x32x16_bf16(a, bh, acc[ntl], 0, 0, 0);
        acc[ntl] = __builtin_amdgcn_mfma_f32_32x32x16_bf16(a, bl, acc[ntl], 0, 0, 0);
      }
      a = na;
      if (s + 1 < 8) block_sync_lds();
    }

    float bmv[4];
#pragma unroll
    for (int ntl = 0; ntl < 4; ++ntl) {
      int nt = nh * 4 + ntl;
      bmv[ntl] = (nt < 4) ? bm[nt * 32 + m] : 0.f;
    }
#pragma unroll
    for (int ntl = 0; ntl < 4; ++ntl) {
      int nt = nh * 4 + ntl;
#pragma unroll
      for (int r = 0; r < 16; ++r) {
        int rowi = (r & 3) + 8 * (r >> 2) + 4 * half;
        z[(size_t)(nb + rg * 32 + rowi) * 256 + nt * 32 + m] =
            (__bf16)(acc[ntl][r] + bmv[ntl]);
      }
    }
  } else {
    // ---- ze: zePre[e] = eaSrt[e] @ Wef, MFMA K=16 ----
    __bf16* Bf = &Bt[0][0];
    ((short8*)Bf)[tid] = ((const short8*)WefS)[tid];
    ((short8*)Bf)[tid + 256] = ((const short8*)WefS)[tid + 256];
    int ebase = (bi - ZDZS_B) * ZEB + wid * 32;
    bf16x8 a = *(const bf16x8*)(eaSrt + (size_t)(ebase + m) * EDIM + half * 8);
    f32x16 acc[4];
#pragma unroll
    for (int nt = 0; nt < 4; ++nt)
#pragma unroll
      for (int r = 0; r < 16; ++r) acc[nt][r] = 0.f;
    block_sync_lds();
#pragma unroll
    for (int nt = 0; nt < 4; ++nt) {
      bf16x8 bh = *(const bf16x8*)&Bf[((0 * 4 + nt) * 64 + lane) * 8];
      bf16x8 bl = *(const bf16x8*)&Bf[((1 * 4 + nt) * 64 + lane) * 8];
      acc[nt] = __builtin_amdgcn_mfma_f32_32x32x16_bf16(a, bh, acc[nt], 0, 0, 0);
      acc[nt] = __builtin_amdgcn_mfma_f32_32x32x16_bf16(a, bl, acc[nt], 0, 0, 0);
    }
#pragma unroll
    for (int nt = 0; nt < 4; ++nt) {
#pragma unroll
      for (int r = 0; r < 16; ++r) {
        int rowi = (r & 3) + 8 * (r >> 2) + 4 * half;
        zePre[(size_t)(ebase + rowi) * H + nt * 32 + m] = (__bf16)acc[nt][r];
      }
    }
  }
}

// ---------------- node-parallel CSR aggregation: aggr[n] = sum relu(zd+zs+ze) ----
// 8-deep gather batches (avg degree 8 -> one L3-latency wait per node).
__global__ __launch_bounds__(256) void edge_aggr_kernel(
    const __bf16* __restrict__ z, const int* __restrict__ srcSrt,
    const int* __restrict__ cend, const __bf16* __restrict__ zePre,
    __bf16* __restrict__ aggrB) {
  int node = blockIdx.x * 4 + (threadIdx.x >> 6);
  int lane = threadIdx.x & 63;
  int c0 = lane * 2;
  int end = cend[node];
  int start = node ? cend[node - 1] : 0;
  v2f acc = {0.f, 0.f};
  if (start < end) {
    v2f zd = bf2f(*(const unsigned*)(z + (size_t)node * 256 + c0));
    int sArr[8];
#pragma unroll
    for (int p = 0; p < 8; ++p)
      if (start + p < end) sArr[p] = srcSrt[start + p];
    for (int e0 = start; e0 < end; e0 += 8) {
      unsigned zsb[8], zeb[8];
#pragma unroll
      for (int p = 0; p < 8; ++p) {
        if (e0 + p < end) {
          zsb[p] = *(const unsigned*)(z + (size_t)sArr[p] * 256 + 128 + c0);
          zeb[p] = *(const unsigned*)(zePre + (size_t)(e0 + p) * H + c0);
        }
      }
#pragma unroll
      for (int p = 0; p < 8; ++p)
        if (e0 + 8 + p < end) sArr[p] = srcSrt[e0 + 8 + p];
#pragma unroll
      for (int p = 0; p < 8; ++p) {
        if (e0 + p < end) {
          v2f t = zd + bf2f(zsb[p]) + bf2f(zeb[p]);
          acc.x += fmaxf(t.x, 0.f);
          acc.y += fmaxf(t.y, 0.f);
        }
      }
    }
  }
  union { __bf16 b[2]; unsigned u; } pk;
  pk.b[0] = (__bf16)acc.x;
  pk.b[1] = (__bf16)acc.y;
  *(unsigned*)(aggrB + (size_t)node * H + c0) = pk.u;
}

// ---------------- MFMA fused node update (h bf16), 64 rows/block ----------------
// (R9 version -- the pool-fusion epilogue regressed this kernel 40 -> 65 us.)
__global__ __launch_bounds__(256) void node_update_mfma_kernel(
    __bf16* __restrict__ hb, const __bf16* __restrict__ aggrB,
    const int* __restrict__ deg, const __bf16* __restrict__ WnS,
    const float* __restrict__ ub1, const float* __restrict__ va,
    const float* __restrict__ ub2) {
  __shared__ __align__(16) __bf16 Bt[2][CHUNK_ELEMS];  // 16 KB
  __shared__ __bf16 hid[2][32][132];                   // 16.9 KB
  __shared__ float degS[64];
  int tid = threadIdx.x;
  int nb = blockIdx.x * 64;
  if (tid < 64) degS[tid] = (float)deg[nb + tid];
  int wid = tid >> 6, lane = tid & 63, m = lane & 31, half = lane >> 5;
  int rg = wid & 1;        // row group (32 rows)
  int nh = wid >> 1;       // col half (2 nt slots)
  int row = nb + rg * 32 + m;
  const __bf16* aHb = hb + (size_t)row * H + half * 8;
  const __bf16* aGb = aggrB + (size_t)row * H + half * 8;
  const short8* gW = (const short8*)WnS;
  short8* sB0 = (short8*)&Bt[0][0];
  short8* sB1 = (short8*)&Bt[1][0];
  sB0[tid] = gW[tid];
  sB0[tid + 256] = gW[tid + 256];
  short8 p0 = gW[512 + tid], p1 = gW[512 + tid + 256];
  float bv1[2], bva[2];
#pragma unroll
  for (int ntl = 0; ntl < 2; ++ntl) {
    int nt = nh * 2 + ntl;
    bv1[ntl] = ub1[nt * 32 + m];
    bva[ntl] = va[nt * 32 + m];
  }
  f32x16 acc[2];
#pragma unroll
  for (int ntl = 0; ntl < 2; ++ntl)
#pragma unroll
    for (int r = 0; r < 16; ++r) acc[ntl][r] = 0.f;
  bf16x8 acur = *(const bf16x8*)aHb;
  block_sync_lds();

  for (int s = 0; s < 16; ++s) {
    int buf = s & 1;
    bf16x8 anext = acur;
    if (s + 1 < 16) {
      int sp = s + 1;
      anext = (sp < 8) ? *(const bf16x8*)(aHb + sp * 16)
                       : *(const bf16x8*)(aGb + (sp - 8) * 16);
    }
    {
      short8* sb = buf ? sB0 : sB1;
      sb[tid] = p0;
      sb[tid + 256] = p1;
      if (s + 2 < NODE_CHUNKS) {
        p0 = gW[(size_t)(s + 2) * 512 + tid];
        p1 = gW[(size_t)(s + 2) * 512 + tid + 256];
      }
    }
    const __bf16* bb = &Bt[buf][0];
#pragma unroll
    for (int ntl = 0; ntl < 2; ++ntl) {
      int nt = nh * 2 + ntl;
      bf16x8 bh = *(const bf16x8*)&bb[((0 * 4 + nt) * 64 + lane) * 8];
      bf16x8 bl = *(const bf16x8*)&bb[((1 * 4 + nt) * 64 + lane) * 8];
      acc[ntl] = __builtin_amdgcn_mfma_f32_32x32x16_bf16(acur, bh, acc[ntl], 0, 0, 0);
      acc[ntl] = __builtin_amdgcn_mfma_f32_32x32x16_bf16(acur, bl, acc[ntl], 0, 0, 0);
    }
    acur = anext;
    block_sync_lds();
  }

#pragma unroll
  for (int ntl = 0; ntl < 2; ++ntl) {
    int nt = nh * 2 + ntl;
#pragma unroll
    for (int r = 0; r < 16; ++r) {
      int rowi = (r & 3) + 8 * (r >> 2) + 4 * half;
      float v = acc[ntl][r] + bv1[ntl] + degS[rg * 32 + rowi] * bva[ntl];
      hid[rg][rowi][nt * 32 + m] = (__bf16)fmaxf(v, 0.f);
      acc[ntl][r] = 0.f;
    }
  }
  // hid cols are split across the two nh waves of each row group ->
  // full barrier before any wave reads hid.
  block_sync_lds();

  for (int s = 16; s < NODE_CHUNKS; ++s) {
    int buf = s & 1;
    if (s + 1 < NODE_CHUNKS) {
      short8* sb = buf ? sB0 : sB1;
      sb[tid] = p0;
      sb[tid + 256] = p1;
      if (s + 2 < NODE_CHUNKS) {
        p0 = gW[(size_t)(s + 2) * 512 + tid];
        p1 = gW[(size_t)(s + 2) * 512 + tid + 256];
      }
    }
    bf16x8 ah = *(const bf16x8*)&hid[rg][m][(s - 16) * 16 + half * 8];
    const __bf16* bb = &Bt[buf][0];
#pragma unroll
    for (int ntl = 0; ntl < 2; ++ntl) {
      int nt = nh * 2 + ntl;
      bf16x8 bh = *(const bf16x8*)&bb[((0 * 4 + nt) * 64 + lane) * 8];
      bf16x8 bl = *(const bf16x8*)&bb[((1 * 4 + nt) * 64 + lane) * 8];
      acc[ntl] = __builtin_amdgcn_mfma_f32_32x32x16_bf16(ah, bh, acc[ntl], 0, 0, 0);
      acc[ntl] = __builtin_amdgcn_mfma_f32_32x32x16_bf16(ah, bl, acc[ntl], 0, 0, 0);
    }
    if (s + 1 < NODE_CHUNKS) block_sync_lds();
  }

#pragma unroll
  for (int ntl = 0; ntl < 2; ++ntl) {
    int nt = nh * 2 + ntl;
    float b2 = ub2[nt * 32 + m];
#pragma unroll
    for (int r = 0; r < 16; ++r) {
      int rowi = (r & 3) + 8 * (r >> 2) + 4 * half;
      size_t idx = (size_t)(nb + rg * 32 + rowi) * H + nt * 32 + m;
      float hv = (float)hb[idx];
      hb[idx] = (__bf16)(hv + acc[ntl][r] + b2);
    }
  }
}

// ---------------- batch mean pooling (batch is sorted) ----------------
__global__ __launch_bounds__(256) void pool_kernel(
    const __bf16* __restrict__ hb, const int* __restrict__ batch,
    float* __restrict__ pooled, int* __restrict__ counts) {
  __shared__ float pS[NBATCH * H];
  __shared__ int cS[NBATCH];
  int tid = threadIdx.x;
  for (int i = tid; i < NBATCH * H; i += 256) pS[i] = 0.f;
  if (tid < NBATCH) cS[tid] = 0;
  __syncthreads();
  int c = tid & 15;
  int r0 = tid >> 4;
  int nbase = blockIdx.x * 128;
  v2f acc4[4] = {{0.f, 0.f}, {0.f, 0.f}, {0.f, 0.f}, {0.f, 0.f}};
  int cnt = 0;
  int cur = -1;
#pragma unroll
  for (int i = 0; i < 8; ++i) {
    int n = nbase + i * 16 + r0;
    if (n >= NN) break;
    int b = batch[n];
    if (b != cur) {
      if (cur >= 0) {
#pragma unroll
        for (int q = 0; q < 4; ++q) {
          atomicAdd(&pS[cur * H + c * 8 + q * 2], acc4[q].x);
          atomicAdd(&pS[cur * H + c * 8 + q * 2 + 1], acc4[q].y);
          acc4[q].x = 0.f;
          acc4[q].y = 0.f;
        }
        if (c == 0) atomicAdd(&cS[cur], cnt);
        cnt = 0;
      }
      cur = b;
    }
    uint4 v = *(const uint4*)(hb + (size_t)n * H + c * 8);
    acc4[0] += bf2f(v.x);
    acc4[1] += bf2f(v.y);
    acc4[2] += bf2f(v.z);
    acc4[3] += bf2f(v.w);
    cnt++;
  }
  if (cur >= 0) {
#pragma unroll
    for (int q = 0; q < 4; ++q) {
      atomicAdd(&pS[cur * H + c * 8 + q * 2], acc4[q].x);
      atomicAdd(&pS[cur * H + c * 8 + q * 2 + 1], acc4[q].y);
    }
    if (c == 0) atomicAdd(&cS[cur], cnt);
  }
  __syncthreads();
  for (int i = tid; i < NBATCH * H; i += 256) {
    float v = pS[i];
    if (v != 0.f) unsafeAtomicAdd(&pooled[i], v);
  }
  if (tid < NBATCH) {
    int cv = cS[tid];
    if (cv) atomicAdd(&counts[tid], cv);
  }
}

// ---------------- readout MLP: one block per batch ----------------
__global__ __launch_bounds__(128) void readout_kernel(
    const float* __restrict__ pooled, const int* __restrict__ counts,
    const float* __restrict__ gf, const float* __restrict__ Wg,
    const float* __restrict__ bg, const float* __restrict__ rW1,
    const float* __restrict__ rb1, const float* __restrict__ rW2,
    const float* __restrict__ rb2, const float* __restrict__ rW3,
    const float* __restrict__ rb3, float* __restrict__ out) {
  __shared__ float fin[256];
  __shared__ float t1[128];
  __shared__ float t2[64];
  int j = threadIdx.x;
  int b = blockIdx.x;
  float cnt = (float)counts[b];
  if (cnt < 1.f) cnt = 1.f;
  fin[j] = pooled[b * H + j] / cnt;
  fin[H + j] = fmaf(gf[b], Wg[j], bg[j]);
  __syncthreads();
  float a = rb1[j];
  for (int k = 0; k < 256; ++k) a = fmaf(fin[k], rW1[k * H + j], a);
  t1[j] = fmaxf(a, 0.f);
  __syncthreads();
  if (j < 64) {
    float a2 = rb2[j];
    for (int k = 0; k < 128; ++k) a2 = fmaf(t1[k], rW2[k * 64 + j], a2);
    t2[j] = fmaxf(a2, 0.f);
  }
  __syncthreads();
  if (j < 64) {
    float p = t2[j] * rW3[j];
#pragma unroll
    for (int off = 32; off; off >>= 1) p += __shfl_down(p, off);
    if (j == 0) out[b] = p + rb3[0];
  }
}

extern "C" void kernel_launch(void* const* d_in, const int* in_sizes, int n_in,
                              void* d_out, int out_size, void* d_ws, size_t ws_size,
                              hipStream_t stream) {
  const float* x   = (const float*)d_in[0];
  const float* ea  = (const float*)d_in[1];
  const float* gf  = (const float*)d_in[2];
  const int*   ei  = (const int*)d_in[3];
  const int*   bat = (const int*)d_in[4];
  const float* Wn  = (const float*)d_in[5];
  const float* bn  = (const float*)d_in[6];
  const float* We  = (const float*)d_in[7];
  const float* be  = (const float*)d_in[8];
  const float* Wg  = (const float*)d_in[9];
  const float* bg  = (const float*)d_in[10];
  const float* mW1 = (const float*)d_in[11];
  const float* mb1 = (const float*)d_in[12];
  const float* mW2 = (const float*)d_in[13];
  const float* mb2 = (const float*)d_in[14];
  const float* uW1 = (const float*)d_in[15];
  const float* ub1 = (const float*)d_in[16];
  const float* uW2 = (const float*)d_in[17];
  const float* ub2 = (const float*)d_in[18];
  const float* rW1 = (const float*)d_in[19];
  const float* rb1 = (const float*)d_in[20];
  const float* rW2 = (const float*)d_in[21];
  const float* rb2 = (const float*)d_in[22];
  const float* rW3 = (const float*)d_in[23];
  const float* rb3 = (const float*)d_in[24];

  char* p = (char*)d_ws;
  __bf16* hb     = (__bf16*)p; p += (size_t)NPAD * H * 2;        // 12.8 MB
  __bf16* aggrB  = (__bf16*)p; p += (size_t)NPAD * H * 2;        // 12.8 MB
  __bf16* z      = (__bf16*)p; p += (size_t)NPAD * 256 * 2;      // 25.6 MB
  __bf16* zePre  = (__bf16*)p; p += (size_t)NE * H * 2;          // 102.4 MB
  __bf16* eaSrt  = (__bf16*)p; p += (size_t)NE * EDIM * 2;       // 12.8 MB
  int*    srcSrt = (int*)p;    p += (size_t)NE * 4;              // 1.6 MB
  __bf16* ZW     = (__bf16*)p; p += (size_t)NLAYERS * 8 * ZW_CHUNK * 2;
  __bf16* WnS    = (__bf16*)p; p += (size_t)NLAYERS * NODE_CHUNKS * CHUNK_ELEMS * 2;
  __bf16* WefS   = (__bf16*)p; p += (size_t)NLAYERS * CHUNK_ELEMS * 2;
  float*  bm     = (float*)p;  p += (size_t)NLAYERS * H * 4;
  float*  Wu     = (float*)p;  p += (size_t)NLAYERS * 256 * H * 4;
  float*  va     = (float*)p;  p += (size_t)NLAYERS * H * 4;
  int*    deg    = (int*)p;    p += (size_t)NPAD * 4;
  int*    cursor = (int*)p;    p += (size_t)NPAD * 4;
  int*    bsum   = (int*)p;    p += 256 * 4;
  float*  pooled = (float*)p;  p += (size_t)NBATCH * H * 4;
  int*    counts = (int*)p;    p += 64;

  hipMemsetAsync(deg, 0, (size_t)NPAD * 4, stream);
  hipMemsetAsync(cursor, 0, (size_t)NPAD * 4, stream);  // tail stays 0 -> empty segments for pad nodes
  hipMemsetAsync(pooled, 0, (size_t)NBATCH * H * 4, stream);
  hipMemsetAsync(counts, 0, 64, stream);

  p1_kernel<<<P1_B, 256, 0, stream>>>(x, Wn, bn, hb, ei, deg, mW1, ZW, mb1, We,
                                      be, WefS, bm, uW1, mW2, mb2, Wu, va);
  k2_kernel<<<K2_B, 256, 0, stream>>>(deg, bsum, Wu, uW2, WnS);
  scan3_kernel<<<NSB, 256, 0, stream>>>(deg, bsum, cursor);
  scatter_kernel<<<(NE + 255) / 256, 256, 0, stream>>>(ei, cursor, srcSrt, ea,
                                                       eaSrt);

  for (int l = 0; l < NLAYERS; ++l) {
    zz_kernel<<<ZZ_B, 256, 0, stream>>>(
        hb, ZW + (size_t)l * 8 * ZW_CHUNK, bm + (size_t)l * H, z,
        eaSrt, WefS + (size_t)l * CHUNK_ELEMS, zePre);
    edge_aggr_kernel<<<NPAD / 4, 256, 0, stream>>>(
        z, srcSrt, cursor, zePre, aggrB);
    node_update_mfma_kernel<<<NPAD / 64, 256, 0, stream>>>(
        hb, aggrB, deg, WnS + (size_t)l * NODE_CHUNKS * CHUNK_ELEMS,
        ub1 + (size_t)l * H, va + (size_t)l * H, ub2 + (size_t)l * H);
  }

  pool_kernel<<<NPAD / 128, 256, 0, stream>>>(hb, bat, pooled, counts);
  readout_kernel<<<NBATCH, 128, 0, stream>>>(pooled, counts, gf, Wg, bg, rW1,
                                             rb1, rW2, rb2, rW3, rb3,
                                             (float*)d_out);
}

// Round 13
// 468.879 us; speedup vs baseline: 2.2938x; 1.0591x over previous
//
#include <hip/hip_runtime.h>

#define NN 50000
#define NPAD 50048     // 391 * 128
#define NE 400000
#define NBATCH 8
#define NDIM 32
#define EDIM 16
#define H 128
#define NLAYERS 3
#define CHUNK_ELEMS 4096   // node-kernel weight chunk: 2 hilo * 4 nt * 64 lane * 8
#define NODE_CHUNKS 24     // 16 (Wu, K=256) + 8 (uW2, K=128)
#define ZW_CHUNK 8192      // zdzs chunk: 2 hilo * 8 nt * 64 lane * 8
#define NSB 196            // scan blocks: ceil(50000/256)
#define ZEB 128            // edges per block in ze path (4 waves x 32)

// fused-grid block counts -- HEAVY BRANCHES FIRST (wu has the longest serial
// per-block work; putting it at the grid tail made it a low-parallelism
// straggler after the cheap embed/degree blocks drained).
#define WUB (NLAYERS * 257)            // 771
#define WEFB NLAYERS                   // 3 (wef + fused wefs swizzle)
#define ZWB (NLAYERS * 8)              // 24
#define EMB_B 1563                     // embed: 32 nodes/block
#define DEG_B 1563                     // degree: 256 edges/block
#define P1_B (WUB + WEFB + ZWB + EMB_B + DEG_B)   // 3924
#define K2_B (NSB + NLAYERS * NODE_CHUNKS)        // 268 (scan1 | wns)
#define ZDZS_B (NPAD / 64)             // 782
#define ZE_B (NE / ZEB)                // 3125
#define ZZ_B (ZDZS_B + ZE_B)           // 3907

typedef __attribute__((ext_vector_type(8))) __bf16 bf16x8;
typedef __attribute__((ext_vector_type(16))) float f32x16;
typedef __attribute__((ext_vector_type(8))) short short8;
typedef __attribute__((ext_vector_type(2))) float v2f;

__device__ __forceinline__ void block_sync_lds() {
  asm volatile("s_waitcnt lgkmcnt(0)\ns_barrier" ::: "memory");
}
// one dword = 2 packed bf16 -> 2 fp32 (pure bit ops)
__device__ __forceinline__ v2f bf2f(unsigned u) {
  v2f r;
  r.x = __uint_as_float(u << 16);
  r.y = __uint_as_float(u & 0xffff0000u);
  return r;
}

// ================= P1: wu | wef(+wefs) | zw | embed | degree ===
__global__ __launch_bounds__(256) void p1_kernel(
    const float* __restrict__ x, const float* __restrict__ Wn,
    const float* __restrict__ bn, __bf16* __restrict__ hb,
    const int* __restrict__ ei, int* __restrict__ deg,
    const float* __restrict__ mW1, __bf16* __restrict__ ZW,
    const float* __restrict__ mb1, const float* __restrict__ We,
    const float* __restrict__ be, __bf16* __restrict__ WefS,
    float* __restrict__ bm, const float* __restrict__ uW1,
    const float* __restrict__ mW2, const float* __restrict__ mb2,
    float* __restrict__ Wu, float* __restrict__ va) {
  __shared__ __align__(16) float smem[NDIM * H + 32 * NDIM];  // 20 KB
  int bi = blockIdx.x;
  int tid = threadIdx.x;
  if (bi < WUB) {
    // ---- folded update weights (fp32 Wu / va): half-split K, LDS row ----
    int l = bi / 257;
    int r = bi % 257;
    int j = tid & 127, hf = tid >> 7;
    const float* u1 = uW1 + (size_t)l * 256 * H;
    if (r < 128) {
      if (tid < 128) Wu[((size_t)l * 256 + r) * H + j] = u1[(size_t)r * H + j];
    } else {
      float* rowS = smem;        // 128: broadcast row
      float* redS = smem + 128;  // 128: cross-half partial
      if (tid < 128)
        rowS[tid] = (r < 256) ? mW2[((size_t)l * H + (r - 128)) * H + tid]
                              : mb2[l * H + tid];
      __syncthreads();
      int cb = hf * 64;
      float s0 = 0.f, s1 = 0.f, s2 = 0.f, s3 = 0.f;
      for (int c = 0; c < 64; c += 4) {
        float a0 = u1[(size_t)(128 + cb + c + 0) * H + j];
        float a1 = u1[(size_t)(128 + cb + c + 1) * H + j];
        float a2 = u1[(size_t)(128 + cb + c + 2) * H + j];
        float a3 = u1[(size_t)(128 + cb + c + 3) * H + j];
        s0 = fmaf(rowS[cb + c + 0], a0, s0);
        s1 = fmaf(rowS[cb + c + 1], a1, s1);
        s2 = fmaf(rowS[cb + c + 2], a2, s2);
        s3 = fmaf(rowS[cb + c + 3], a3, s3);
      }
      float s = (s0 + s1) + (s2 + s3);
      if (hf == 1) redS[j] = s;
      __syncthreads();
      if (hf == 0) {
        float tot = s + redS[j];
        if (r < 256) Wu[((size_t)l * 256 + r) * H + j] = tot;
        else va[l * H + j] = tot;
      }
    }
  } else if (bi < WUB + WEFB) {
    // ---- Wef = We @ mW1[256:384] -> swizzled WefS directly (LDS transpose) ----
    int l = bi - WUB;
    float* WeS = smem;            // 2048
    float* beS = smem + 2048;     // 128
    float* wefT = smem + 2176;    // 2048: Wef[k][n] transpose buffer
    for (int f = tid; f < EDIM * H; f += 256) WeS[f] = We[f];
    if (tid < 128) beS[tid] = be[tid];
    __syncthreads();
    if (tid < 128) {
      int n = tid;
      const float* w1 = mW1 + (size_t)l * 384 * H + (size_t)256 * H + n;
      float acc[EDIM];
#pragma unroll
      for (int i = 0; i < EDIM; ++i) acc[i] = 0.f;
      float accb = 0.f;
      for (int c = 0; c < H; c += 4) {
        float w0 = w1[(size_t)(c + 0) * H];
        float w1v = w1[(size_t)(c + 1) * H];
        float w2 = w1[(size_t)(c + 2) * H];
        float w3 = w1[(size_t)(c + 3) * H];
        accb = fmaf(beS[c + 0], w0, accb);
        accb = fmaf(beS[c + 1], w1v, accb);
        accb = fmaf(beS[c + 2], w2, accb);
        accb = fmaf(beS[c + 3], w3, accb);
#pragma unroll
        for (int i = 0; i < EDIM; ++i) {
          acc[i] = fmaf(WeS[i * H + c + 0], w0, acc[i]);
          acc[i] = fmaf(WeS[i * H + c + 1], w1v, acc[i]);
          acc[i] = fmaf(WeS[i * H + c + 2], w2, acc[i]);
          acc[i] = fmaf(WeS[i * H + c + 3], w3, acc[i]);
        }
      }
#pragma unroll
      for (int i = 0; i < EDIM; ++i) wefT[i * H + n] = acc[i];
      bm[l * H + n] = mb1[l * H + n] + accb;
    }
    __syncthreads();
    {
      int nt = tid >> 6, lane = tid & 63;
      int n = nt * 32 + (lane & 31);
      int half = lane >> 5;
      __bf16* dst = WefS + (size_t)l * CHUNK_ELEMS;
#pragma unroll
      for (int j = 0; j < 8; ++j) {
        int k = half * 8 + j;
        float w = wefT[k * H + n];
        __bf16 hi = (__bf16)w;
        __bf16 lo = (__bf16)(w - (float)hi);
        dst[((0 * 4 + nt) * 64 + lane) * 8 + j] = hi;
        dst[((1 * 4 + nt) * 64 + lane) * 8 + j] = lo;
      }
    }
  } else if (bi < WUB + WEFB + ZWB) {
    // ---- zdzs weights: mW1[0:256] -> hi/lo bf16, frag-swizzled ----
    int bb = bi - WUB - WEFB;
    int l = bb / 8;
    int c = bb % 8;
    const float* w1 = mW1 + (size_t)l * 384 * H;
    __bf16* dst = ZW + ((size_t)l * 8 + c) * ZW_CHUNK;
    for (int it = 0; it < 32; it += 4) {
      float wv[4];
#pragma unroll
      for (int q = 0; q < 4; ++q) {
        int flat = (it + q) * 256 + tid;
        int j = flat & 7;
        int lane = (flat >> 3) & 63;
        int nt = (flat >> 9) & 7;
        int k = c * 16 + ((lane >> 5) << 3) + j;
        int n = nt * 32 + (lane & 31);
        wv[q] = (n < 128) ? w1[(size_t)k * H + n]
                          : w1[(size_t)(128 + k) * H + (n - 128)];
      }
#pragma unroll
      for (int q = 0; q < 4; ++q) {
        int flat = (it + q) * 256 + tid;
        int hilo = flat >> 12;
        __bf16 hi = (__bf16)wv[q];
        __bf16 lo = (__bf16)(wv[q] - (float)hi);
        dst[flat] = hilo ? lo : hi;
      }
    }
  } else if (bi < WUB + WEFB + ZWB + EMB_B) {
    // ---- embed: h = x @ Wn + bn, 32 nodes/block ----
    int eb = bi - WUB - WEFB - ZWB;
    float* Ws = smem;
    float* xs = smem + NDIM * H;
    int nbase = eb * 32;
    for (int f = tid; f < NDIM * H; f += 256) Ws[f] = Wn[f];
    for (int f = tid; f < 32 * NDIM; f += 256) {
      int gi = nbase * NDIM + f;
      xs[f] = (gi < NN * NDIM) ? x[gi] : 0.f;
    }
    __syncthreads();
    int j = tid & 127, g = tid >> 7;
    float wcol[NDIM];
#pragma unroll
    for (int k = 0; k < NDIM; ++k) wcol[k] = Ws[k * H + j];
    float b = bn[j];
    for (int nn = 0; nn < 16; ++nn) {
      int node = nbase + g * 16 + nn;
      if (node < NN) {
        float acc = b;
        const float4* xv = (const float4*)&xs[(g * 16 + nn) * NDIM];
#pragma unroll
        for (int k4 = 0; k4 < NDIM / 4; ++k4) {
          float4 v = xv[k4];
          acc = fmaf(v.x, wcol[k4 * 4 + 0], acc);
          acc = fmaf(v.y, wcol[k4 * 4 + 1], acc);
          acc = fmaf(v.z, wcol[k4 * 4 + 2], acc);
          acc = fmaf(v.w, wcol[k4 * 4 + 3], acc);
        }
        hb[(size_t)node * H + j] = (__bf16)acc;
      }
    }
  } else {
    // ---- degree histogram over dst ----
    int e = (bi - WUB - WEFB - ZWB - EMB_B) * 256 + tid;
    if (e < NE) atomicAdd(&deg[ei[NE + e]], 1);
  }
}

// ================= K2: scan1 | precomp_wns ===
__global__ __launch_bounds__(256) void k2_kernel(
    const int* __restrict__ deg, int* __restrict__ bsum,
    const float* __restrict__ Wu, const float* __restrict__ uW2,
    __bf16* __restrict__ WnS) {
  __shared__ int ws[4];
  int bi = blockIdx.x;
  int tid = threadIdx.x;
  if (bi < NSB) {
    // ---- scan1: per-block degree sums ----
    int i = bi * 256 + tid;
    int lane = tid & 63, wid = tid >> 6;
    int v = (i < NN) ? deg[i] : 0;
#pragma unroll
    for (int off = 32; off; off >>= 1) v += __shfl_down(v, off);
    if (lane == 0) ws[wid] = v;
    __syncthreads();
    if (tid == 0) bsum[bi] = ws[0] + ws[1] + ws[2] + ws[3];
  } else {
    // ---- swizzle node weights into hi/lo frag chunks ----
    int idx = bi - NSB;
    int l = idx / NODE_CHUNKS;
    int c = idx % NODE_CHUNKS;
    int nt = tid >> 6, lane = tid & 63;
    int n = nt * 32 + (lane & 31);
    int half = lane >> 5;
    __bf16* dst = WnS + ((size_t)l * NODE_CHUNKS + c) * CHUNK_ELEMS;
#pragma unroll
    for (int j = 0; j < 8; ++j) {
      float w;
      if (c < 16) {
        int k = c * 16 + half * 8 + j;
        w = Wu[((size_t)l * 256 + k) * H + n];
      } else {
        int k = (c - 16) * 16 + half * 8 + j;
        w = uW2[((size_t)l * H + k) * H + n];
      }
      __bf16 hi = (__bf16)w;
      __bf16 lo = (__bf16)(w - (float)hi);
      dst[((0 * 4 + nt) * 64 + lane) * 8 + j] = hi;
      dst[((1 * 4 + nt) * 64 + lane) * 8 + j] = lo;
    }
  }
}

// ---------------- scan3 (with scan2 folded in: each block scans bsum locally) ----
__global__ __launch_bounds__(256) void scan3_kernel(const int* __restrict__ deg,
                                                    const int* __restrict__ bsum,
                                                    int* __restrict__ cursor) {
  __shared__ int s[256];
  __shared__ int wsum[4], woff[4];
  int t = threadIdx.x;
  int bv = (t < NSB) ? bsum[t] : 0;
  s[t] = bv;
  __syncthreads();
  for (int off = 1; off < 256; off <<= 1) {
    int u = (t >= off) ? s[t - off] : 0;
    __syncthreads();
    s[t] += u;
    __syncthreads();
  }
  int boff_b = s[blockIdx.x] - bsum[blockIdx.x];  // exclusive prefix for this block
  __syncthreads();

  int i = blockIdx.x * 256 + t;
  int lane = t & 63, wid = t >> 6;
  int orig = (i < NN) ? deg[i] : 0;
  int v = orig;
#pragma unroll
  for (int off = 1; off < 64; off <<= 1) {
    int u = __shfl_up(v, off);
    if (lane >= off) v += u;
  }
  if (lane == 63) wsum[wid] = v;
  __syncthreads();
  if (t == 0) {
    int r = 0;
#pragma unroll
    for (int w = 0; w < 4; ++w) {
      woff[w] = r;
      r += wsum[w];
    }
  }
  __syncthreads();
  if (i < NN) cursor[i] = (v - orig) + woff[wid] + boff_b;
}

// ---------------- counting-sort scatter + ea gather fused ----------------
__global__ __launch_bounds__(256) void scatter_kernel(
    const int* __restrict__ ei, int* __restrict__ cursor,
    int* __restrict__ srcSrt, const float* __restrict__ ea,
    __bf16* __restrict__ eaSrt) {
  int e = blockIdx.x * 256 + threadIdx.x;
  if (e < NE) {
    int d = ei[NE + e];
    int s = ei[e];
    const float4* ep = (const float4*)(ea + (size_t)e * EDIM);
    float4 v0 = ep[0], v1 = ep[1], v2 = ep[2], v3 = ep[3];
    int pos = atomicAdd(&cursor[d], 1);
    srcSrt[pos] = s;
    union { __bf16 b[16]; uint4 u[2]; } pk;
    pk.b[0] = (__bf16)v0.x;  pk.b[1] = (__bf16)v0.y;
    pk.b[2] = (__bf16)v0.z;  pk.b[3] = (__bf16)v0.w;
    pk.b[4] = (__bf16)v1.x;  pk.b[5] = (__bf16)v1.y;
    pk.b[6] = (__bf16)v1.z;  pk.b[7] = (__bf16)v1.w;
    pk.b[8] = (__bf16)v2.x;  pk.b[9] = (__bf16)v2.y;
    pk.b[10] = (__bf16)v2.z; pk.b[11] = (__bf16)v2.w;
    pk.b[12] = (__bf16)v3.x; pk.b[13] = (__bf16)v3.y;
    pk.b[14] = (__bf16)v3.z; pk.b[15] = (__bf16)v3.w;
    uint4* op = (uint4*)(eaSrt + (size_t)pos * EDIM);
    op[0] = pk.u[0];
    op[1] = pk.u[1];
  }
}

// ================= ZZ: zdzs (782 blocks) | ze (3125 blocks), one dispatch =====
__global__ __launch_bounds__(256) void zz_kernel(
    const __bf16* __restrict__ hb, const __bf16* __restrict__ ZW,
    const float* __restrict__ bm, __bf16* __restrict__ z,
    const __bf16* __restrict__ eaSrt, const __bf16* __restrict__ WefS,
    __bf16* __restrict__ zePre) {
  __shared__ __align__(16) __bf16 Bt[2][ZW_CHUNK];  // 32 KB
  int bi = blockIdx.x;
  int tid = threadIdx.x;
  int wid = tid >> 6, lane = tid & 63, m = lane & 31, half = lane >> 5;
  if (bi < ZDZS_B) {
    // ---- zdzs: z = h @ [W_d|W_s] (+bm on dst half), 64 rows/block ----
    int rg = wid & 1;   // 32-row group
    int nh = wid >> 1;  // nt quad
    int nb = bi * 64;
    int row = nb + rg * 32 + m;
    const __bf16* aH = hb + (size_t)row * H + half * 8;
    const short8* gW = (const short8*)ZW;  // 1024 short8 per chunk
    short8* sB0 = (short8*)&Bt[0][0];
    short8* sB1 = (short8*)&Bt[1][0];
#pragma unroll
    for (int q = 0; q < 4; ++q) sB0[tid + q * 256] = gW[tid + q * 256];
    short8 p0 = gW[1024 + tid], p1 = gW[1024 + tid + 256];
    short8 p2 = gW[1024 + tid + 512], p3 = gW[1024 + tid + 768];
    f32x16 acc[4];
#pragma unroll
    for (int ntl = 0; ntl < 4; ++ntl)
#pragma unroll
      for (int r = 0; r < 16; ++r) acc[ntl][r] = 0.f;
    bf16x8 a = *(const bf16x8*)aH;
    block_sync_lds();

    for (int s = 0; s < 8; ++s) {
      int buf = s & 1;
      bf16x8 na = a;
      if (s + 1 < 8) na = *(const bf16x8*)(aH + (s + 1) * 16);
      if (s + 1 < 8) {
        short8* sb = buf ? sB0 : sB1;
        sb[tid] = p0;
        sb[tid + 256] = p1;
        sb[tid + 512] = p2;
        sb[tid + 768] = p3;
        if (s + 2 < 8) {
          p0 = gW[(size_t)(s + 2) * 1024 + tid];
          p1 = gW[(size_t)(s + 2) * 1024 + tid + 256];
          p2 = gW[(size_t)(s + 2) * 1024 + tid + 512];
          p3 = gW[(size_t)(s + 2) * 1024 + tid + 768];
        }
      }
      const __bf16* bb = &Bt[buf][0];
#pragma unroll
      for (int ntl = 0; ntl < 4; ++ntl) {
        int nt = nh * 4 + ntl;
        bf16x8 bh = *(const bf16x8*)&bb[((0 * 8 + nt) * 64 + lane) * 8];
        bf16x8 bl = *(const bf16x8*)&bb[((1 * 8 + nt) * 64 + lane) * 8];
        acc[ntl] = __builtin_amdgcn_mfma_f32_32x32x16_bf16(a, bh, acc[ntl], 0, 0, 0);
        acc[ntl] = __builtin_amdgcn_mfma_f32_32x32x16_bf16(a, bl, acc[ntl], 0, 0, 0);
      }
      a = na;
      if (s + 1 < 8) block_sync_lds();
    }

    float bmv[4];
#pragma unroll
    for (int ntl = 0; ntl < 4; ++ntl) {
      int nt = nh * 4 + ntl;
      bmv[ntl] = (nt < 4) ? bm[nt * 32 + m] : 0.f;
    }
#pragma unroll
    for (int ntl = 0; ntl < 4; ++ntl) {
      int nt = nh * 4 + ntl;
#pragma unroll
      for (int r = 0; r < 16; ++r) {
        int rowi = (r & 3) + 8 * (r >> 2) + 4 * half;
        z[(size_t)(nb + rg * 32 + rowi) * 256 + nt * 32 + m] =
            (__bf16)(acc[ntl][r] + bmv[ntl]);
      }
    }
  } else {
    // ---- ze: zePre[e] = eaSrt[e] @ Wef, MFMA K=16 ----
    __bf16* Bf = &Bt[0][0];
    ((short8*)Bf)[tid] = ((const short8*)WefS)[tid];
    ((short8*)Bf)[tid + 256] = ((const short8*)WefS)[tid + 256];
    int ebase = (bi - ZDZS_B) * ZEB + wid * 32;
    bf16x8 a = *(const bf16x8*)(eaSrt + (size_t)(ebase + m) * EDIM + half * 8);
    f32x16 acc[4];
#pragma unroll
    for (int nt = 0; nt < 4; ++nt)
#pragma unroll
      for (int r = 0; r < 16; ++r) acc[nt][r] = 0.f;
    block_sync_lds();
#pragma unroll
    for (int nt = 0; nt < 4; ++nt) {
      bf16x8 bh = *(const bf16x8*)&Bf[((0 * 4 + nt) * 64 + lane) * 8];
      bf16x8 bl = *(const bf16x8*)&Bf[((1 * 4 + nt) * 64 + lane) * 8];
      acc[nt] = __builtin_amdgcn_mfma_f32_32x32x16_bf16(a, bh, acc[nt], 0, 0, 0);
      acc[nt] = __builtin_amdgcn_mfma_f32_32x32x16_bf16(a, bl, acc[nt], 0, 0, 0);
    }
#pragma unroll
    for (int nt = 0; nt < 4; ++nt) {
#pragma unroll
      for (int r = 0; r < 16; ++r) {
        int rowi = (r & 3) + 8 * (r >> 2) + 4 * half;
        zePre[(size_t)(ebase + rowi) * H + nt * 32 + m] = (__bf16)acc[nt][r];
      }
    }
  }
}

// ---------------- node-parallel CSR aggregation: aggr[n] = sum relu(zd+zs+ze) ----
// 4-deep gather batches (R9-measured config; 8-deep cost ~7 us -- extra VGPR
// pressure with no additional MLP for avg-degree-8 nodes).
__global__ __launch_bounds__(256) void edge_aggr_kernel(
    const __bf16* __restrict__ z, const int* __restrict__ srcSrt,
    const int* __restrict__ cend, const __bf16* __restrict__ zePre,
    __bf16* __restrict__ aggrB) {
  int node = blockIdx.x * 4 + (threadIdx.x >> 6);
  int lane = threadIdx.x & 63;
  int c0 = lane * 2;
  int end = cend[node];
  int start = node ? cend[node - 1] : 0;
  v2f acc = {0.f, 0.f};
  if (start < end) {
    v2f zd = bf2f(*(const unsigned*)(z + (size_t)node * 256 + c0));
    int sArr[4];
#pragma unroll
    for (int p = 0; p < 4; ++p)
      if (start + p < end) sArr[p] = srcSrt[start + p];
    for (int e0 = start; e0 < end; e0 += 4) {
      unsigned zsb[4], zeb[4];
#pragma unroll
      for (int p = 0; p < 4; ++p) {
        if (e0 + p < end) {
          zsb[p] = *(const unsigned*)(z + (size_t)sArr[p] * 256 + 128 + c0);
          zeb[p] = *(const unsigned*)(zePre + (size_t)(e0 + p) * H + c0);
        }
      }
#pragma unroll
      for (int p = 0; p < 4; ++p)
        if (e0 + 4 + p < end) sArr[p] = srcSrt[e0 + 4 + p];
#pragma unroll
      for (int p = 0; p < 4; ++p) {
        if (e0 + p < end) {
          v2f t = zd + bf2f(zsb[p]) + bf2f(zeb[p]);
          acc.x += fmaxf(t.x, 0.f);
          acc.y += fmaxf(t.y, 0.f);
        }
      }
    }
  }
  union { __bf16 b[2]; unsigned u; } pk;
  pk.b[0] = (__bf16)acc.x;
  pk.b[1] = (__bf16)acc.y;
  *(unsigned*)(aggrB + (size_t)node * H + c0) = pk.u;
}

// ---------------- MFMA fused node update (h bf16), 64 rows/block ----------------
__global__ __launch_bounds__(256) void node_update_mfma_kernel(
    __bf16* __restrict__ hb, const __bf16* __restrict__ aggrB,
    const int* __restrict__ deg, const __bf16* __restrict__ WnS,
    const float* __restrict__ ub1, const float* __restrict__ va,
    const float* __restrict__ ub2) {
  __shared__ __align__(16) __bf16 Bt[2][CHUNK_ELEMS];  // 16 KB
  __shared__ __bf16 hid[2][32][132];                   // 16.9 KB
  __shared__ float degS[64];
  int tid = threadIdx.x;
  int nb = blockIdx.x * 64;
  if (tid < 64) degS[tid] = (float)deg[nb + tid];
  int wid = tid >> 6, lane = tid & 63, m = lane & 31, half = lane >> 5;
  int rg = wid & 1;        // row group (32 rows)
  int nh = wid >> 1;       // col half (2 nt slots)
  int row = nb + rg * 32 + m;
  const __bf16* aHb = hb + (size_t)row * H + half * 8;
  const __bf16* aGb = aggrB + (size_t)row * H + half * 8;
  const short8* gW = (const short8*)WnS;
  short8* sB0 = (short8*)&Bt[0][0];
  short8* sB1 = (short8*)&Bt[1][0];
  sB0[tid] = gW[tid];
  sB0[tid + 256] = gW[tid + 256];
  short8 p0 = gW[512 + tid], p1 = gW[512 + tid + 256];
  float bv1[2], bva[2];
#pragma unroll
  for (int ntl = 0; ntl < 2; ++ntl) {
    int nt = nh * 2 + ntl;
    bv1[ntl] = ub1[nt * 32 + m];
    bva[ntl] = va[nt * 32 + m];
  }
  f32x16 acc[2];
#pragma unroll
  for (int ntl = 0; ntl < 2; ++ntl)
#pragma unroll
    for (int r = 0; r < 16; ++r) acc[ntl][r] = 0.f;
  bf16x8 acur = *(const bf16x8*)aHb;
  block_sync_lds();

  for (int s = 0; s < 16; ++s) {
    int buf = s & 1;
    bf16x8 anext = acur;
    if (s + 1 < 16) {
      int sp = s + 1;
      anext = (sp < 8) ? *(const bf16x8*)(aHb + sp * 16)
                       : *(const bf16x8*)(aGb + (sp - 8) * 16);
    }
    {
      short8* sb = buf ? sB0 : sB1;
      sb[tid] = p0;
      sb[tid + 256] = p1;
      if (s + 2 < NODE_CHUNKS) {
        p0 = gW[(size_t)(s + 2) * 512 + tid];
        p1 = gW[(size_t)(s + 2) * 512 + tid + 256];
      }
    }
    const __bf16* bb = &Bt[buf][0];
#pragma unroll
    for (int ntl = 0; ntl < 2; ++ntl) {
      int nt = nh * 2 + ntl;
      bf16x8 bh = *(const bf16x8*)&bb[((0 * 4 + nt) * 64 + lane) * 8];
      bf16x8 bl = *(const bf16x8*)&bb[((1 * 4 + nt) * 64 + lane) * 8];
      acc[ntl] = __builtin_amdgcn_mfma_f32_32x32x16_bf16(acur, bh, acc[ntl], 0, 0, 0);
      acc[ntl] = __builtin_amdgcn_mfma_f32_32x32x16_bf16(acur, bl, acc[ntl], 0, 0, 0);
    }
    acur = anext;
    block_sync_lds();
  }

#pragma unroll
  for (int ntl = 0; ntl < 2; ++ntl) {
    int nt = nh * 2 + ntl;
#pragma unroll
    for (int r = 0; r < 16; ++r) {
      int rowi = (r & 3) + 8 * (r >> 2) + 4 * half;
      float v = acc[ntl][r] + bv1[ntl] + degS[rg * 32 + rowi] * bva[ntl];
      hid[rg][rowi][nt * 32 + m] = (__bf16)fmaxf(v, 0.f);
      acc[ntl][r] = 0.f;
    }
  }
  // hid cols are split across the two nh waves of each row group ->
  // full barrier before any wave reads hid.
  block_sync_lds();

  for (int s = 16; s < NODE_CHUNKS; ++s) {
    int buf = s & 1;
    if (s + 1 < NODE_CHUNKS) {
      short8* sb = buf ? sB0 : sB1;
      sb[tid] = p0;
      sb[tid + 256] = p1;
      if (s + 2 < NODE_CHUNKS) {
        p0 = gW[(size_t)(s + 2) * 512 + tid];
        p1 = gW[(size_t)(s + 2) * 512 + tid + 256];
      }
    }
    bf16x8 ah = *(const bf16x8*)&hid[rg][m][(s - 16) * 16 + half * 8];
    const __bf16* bb = &Bt[buf][0];
#pragma unroll
    for (int ntl = 0; ntl < 2; ++ntl) {
      int nt = nh * 2 + ntl;
      bf16x8 bh = *(const bf16x8*)&bb[((0 * 4 + nt) * 64 + lane) * 8];
      bf16x8 bl = *(const bf16x8*)&bb[((1 * 4 + nt) * 64 + lane) * 8];
      acc[ntl] = __builtin_amdgcn_mfma_f32_32x32x16_bf16(ah, bh, acc[ntl], 0, 0, 0);
      acc[ntl] = __builtin_amdgcn_mfma_f32_32x32x16_bf16(ah, bl, acc[ntl], 0, 0, 0);
    }
    if (s + 1 < NODE_CHUNKS) block_sync_lds();
  }

#pragma unroll
  for (int ntl = 0; ntl < 2; ++ntl) {
    int nt = nh * 2 + ntl;
    float b2 = ub2[nt * 32 + m];
#pragma unroll
    for (int r = 0; r < 16; ++r) {
      int rowi = (r & 3) + 8 * (r >> 2) + 4 * half;
      size_t idx = (size_t)(nb + rg * 32 + rowi) * H + nt * 32 + m;
      float hv = (float)hb[idx];
      hb[idx] = (__bf16)(hv + acc[ntl][r] + b2);
    }
  }
}

// ---------------- batch mean pooling (batch is sorted) ----------------
__global__ __launch_bounds__(256) void pool_kernel(
    const __bf16* __restrict__ hb, const int* __restrict__ batch,
    float* __restrict__ pooled, int* __restrict__ counts) {
  __shared__ float pS[NBATCH * H];
  __shared__ int cS[NBATCH];
  int tid = threadIdx.x;
  for (int i = tid; i < NBATCH * H; i += 256) pS[i] = 0.f;
  if (tid < NBATCH) cS[tid] = 0;
  __syncthreads();
  int c = tid & 15;
  int r0 = tid >> 4;
  int nbase = blockIdx.x * 128;
  v2f acc4[4] = {{0.f, 0.f}, {0.f, 0.f}, {0.f, 0.f}, {0.f, 0.f}};
  int cnt = 0;
  int cur = -1;
#pragma unroll
  for (int i = 0; i < 8; ++i) {
    int n = nbase + i * 16 + r0;
    if (n >= NN) break;
    int b = batch[n];
    if (b != cur) {
      if (cur >= 0) {
#pragma unroll
        for (int q = 0; q < 4; ++q) {
          atomicAdd(&pS[cur * H + c * 8 + q * 2], acc4[q].x);
          atomicAdd(&pS[cur * H + c * 8 + q * 2 + 1], acc4[q].y);
          acc4[q].x = 0.f;
          acc4[q].y = 0.f;
        }
        if (c == 0) atomicAdd(&cS[cur], cnt);
        cnt = 0;
      }
      cur = b;
    }
    uint4 v = *(const uint4*)(hb + (size_t)n * H + c * 8);
    acc4[0] += bf2f(v.x);
    acc4[1] += bf2f(v.y);
    acc4[2] += bf2f(v.z);
    acc4[3] += bf2f(v.w);
    cnt++;
  }
  if (cur >= 0) {
#pragma unroll
    for (int q = 0; q < 4; ++q) {
      atomicAdd(&pS[cur * H + c * 8 + q * 2], acc4[q].x);
      atomicAdd(&pS[cur * H + c * 8 + q * 2 + 1], acc4[q].y);
    }
    if (c == 0) atomicAdd(&cS[cur], cnt);
  }
  __syncthreads();
  for (int i = tid; i < NBATCH * H; i += 256) {
    float v = pS[i];
    if (v != 0.f) unsafeAtomicAdd(&pooled[i], v);
  }
  if (tid < NBATCH) {
    int cv = cS[tid];
    if (cv) atomicAdd(&counts[tid], cv);
  }
}

// ---------------- readout MLP: one block per batch ----------------
__global__ __launch_bounds__(128) void readout_kernel(
    const float* __restrict__ pooled, const int* __restrict__ counts,
    const float* __restrict__ gf, const float* __restrict__ Wg,
    const float* __restrict__ bg, const float* __restrict__ rW1,
    const float* __restrict__ rb1, const float* __restrict__ rW2,
    const float* __restrict__ rb2, const float* __restrict__ rW3,
    const float* __restrict__ rb3, float* __restrict__ out) {
  __shared__ float fin[256];
  __shared__ float t1[128];
  __shared__ float t2[64];
  int j = threadIdx.x;
  int b = blockIdx.x;
  float cnt = (float)counts[b];
  if (cnt < 1.f) cnt = 1.f;
  fin[j] = pooled[b * H + j] / cnt;
  fin[H + j] = fmaf(gf[b], Wg[j], bg[j]);
  __syncthreads();
  float a = rb1[j];
  for (int k = 0; k < 256; ++k) a = fmaf(fin[k], rW1[k * H + j], a);
  t1[j] = fmaxf(a, 0.f);
  __syncthreads();
  if (j < 64) {
    float a2 = rb2[j];
    for (int k = 0; k < 128; ++k) a2 = fmaf(t1[k], rW2[k * 64 + j], a2);
    t2[j] = fmaxf(a2, 0.f);
  }
  __syncthreads();
  if (j < 64) {
    float p = t2[j] * rW3[j];
#pragma unroll
    for (int off = 32; off; off >>= 1) p += __shfl_down(p, off);
    if (j == 0) out[b] = p + rb3[0];
  }
}

extern "C" void kernel_launch(void* const* d_in, const int* in_sizes, int n_in,
                              void* d_out, int out_size, void* d_ws, size_t ws_size,
                              hipStream_t stream) {
  const float* x   = (const float*)d_in[0];
  const float* ea  = (const float*)d_in[1];
  const float* gf  = (const float*)d_in[2];
  const int*   ei  = (const int*)d_in[3];
  const int*   bat = (const int*)d_in[4];
  const float* Wn  = (const float*)d_in[5];
  const float* bn  = (const float*)d_in[6];
  const float* We  = (const float*)d_in[7];
  const float* be  = (const float*)d_in[8];
  const float* Wg  = (const float*)d_in[9];
  const float* bg  = (const float*)d_in[10];
  const float* mW1 = (const float*)d_in[11];
  const float* mb1 = (const float*)d_in[12];
  const float* mW2 = (const float*)d_in[13];
  const float* mb2 = (const float*)d_in[14];
  const float* uW1 = (const float*)d_in[15];
  const float* ub1 = (const float*)d_in[16];
  const float* uW2 = (const float*)d_in[17];
  const float* ub2 = (const float*)d_in[18];
  const float* rW1 = (const float*)d_in[19];
  const float* rb1 = (const float*)d_in[20];
  const float* rW2 = (const float*)d_in[21];
  const float* rb2 = (const float*)d_in[22];
  const float* rW3 = (const float*)d_in[23];
  const float* rb3 = (const float*)d_in[24];

  char* p = (char*)d_ws;
  __bf16* hb     = (__bf16*)p; p += (size_t)NPAD * H * 2;        // 12.8 MB
  __bf16* aggrB  = (__bf16*)p; p += (size_t)NPAD * H * 2;        // 12.8 MB
  __bf16* z      = (__bf16*)p; p += (size_t)NPAD * 256 * 2;      // 25.6 MB
  __bf16* zePre  = (__bf16*)p; p += (size_t)NE * H * 2;          // 102.4 MB
  __bf16* eaSrt  = (__bf16*)p; p += (size_t)NE * EDIM * 2;       // 12.8 MB
  int*    srcSrt = (int*)p;    p += (size_t)NE * 4;              // 1.6 MB
  __bf16* ZW     = (__bf16*)p; p += (size_t)NLAYERS * 8 * ZW_CHUNK * 2;
  __bf16* WnS    = (__bf16*)p; p += (size_t)NLAYERS * NODE_CHUNKS * CHUNK_ELEMS * 2;
  __bf16* WefS   = (__bf16*)p; p += (size_t)NLAYERS * CHUNK_ELEMS * 2;
  float*  bm     = (float*)p;  p += (size_t)NLAYERS * H * 4;
  float*  Wu     = (float*)p;  p += (size_t)NLAYERS * 256 * H * 4;
  float*  va     = (float*)p;  p += (size_t)NLAYERS * H * 4;
  int*    deg    = (int*)p;    p += (size_t)NPAD * 4;
  int*    cursor = (int*)p;    p += (size_t)NPAD * 4;
  int*    bsum   = (int*)p;    p += 256 * 4;
  float*  pooled = (float*)p;  p += (size_t)NBATCH * H * 4;
  int*    counts = (int*)p;    p += 64;

  hipMemsetAsync(deg, 0, (size_t)NPAD * 4, stream);
  hipMemsetAsync(cursor, 0, (size_t)NPAD * 4, stream);  // tail stays 0 -> empty segments for pad nodes
  hipMemsetAsync(pooled, 0, (size_t)NBATCH * H * 4, stream);
  hipMemsetAsync(counts, 0, 64, stream);

  p1_kernel<<<P1_B, 256, 0, stream>>>(x, Wn, bn, hb, ei, deg, mW1, ZW, mb1, We,
                                      be, WefS, bm, uW1, mW2, mb2, Wu, va);
  k2_kernel<<<K2_B, 256, 0, stream>>>(deg, bsum, Wu, uW2, WnS);
  scan3_kernel<<<NSB, 256, 0, stream>>>(deg, bsum, cursor);
  scatter_kernel<<<(NE + 255) / 256, 256, 0, stream>>>(ei, cursor, srcSrt, ea,
                                                       eaSrt);

  for (int l = 0; l < NLAYERS; ++l) {
    zz_kernel<<<ZZ_B, 256, 0, stream>>>(
        hb, ZW + (size_t)l * 8 * ZW_CHUNK, bm + (size_t)l * H, z,
        eaSrt, WefS + (size_t)l * CHUNK_ELEMS, zePre);
    edge_aggr_kernel<<<NPAD / 4, 256, 0, stream>>>(
        z, srcSrt, cursor, zePre, aggrB);
    node_update_mfma_kernel<<<NPAD / 64, 256, 0, stream>>>(
        hb, aggrB, deg, WnS + (size_t)l * NODE_CHUNKS * CHUNK_ELEMS,
        ub1 + (size_t)l * H, va + (size_t)l * H, ub2 + (size_t)l * H);
  }

  pool_kernel<<<NPAD / 128, 256, 0, stream>>>(hb, bat, pooled, counts);
  readout_kernel<<<NBATCH, 128, 0, stream>>>(pooled, counts, gf, Wg, bg, rW1,
                                             rb1, rW2, rb2, rW3, rb3,
                                             (float*)d_out);
}